// Round 4
// baseline (3396.712 us; speedup 1.0000x reference)
//
#include <hip/hip_runtime.h>

#define NTOT 200000
#define EE   1200000
// 200000 = 64 * 3125 exactly -> no tail guards needed in tile kernels

__device__ __forceinline__ float rcpf(float x) { return __builtin_amdgcn_rcpf(x); }
__device__ __forceinline__ float sigm(float x) { return rcpf(1.f + __expf(-x)); }
__device__ __forceinline__ float tanh_f(float x) { return 1.f - 2.f * rcpf(__expf(2.f * x) + 1.f); }
__device__ __forceinline__ float dot4(float4 a, float4 b) {
    return a.x*b.x + a.y*b.y + a.z*b.z + a.w*b.w;
}

__global__ __launch_bounds__(256) void k_deg_init(float* deg) {
    int n = blockIdx.x*256 + threadIdx.x;
    if (n < NTOT) deg[n] = 1.0f;
}

__global__ __launch_bounds__(256) void k_deg_scatter(const float* __restrict__ ew,
                                                     const int* __restrict__ dst,
                                                     float* __restrict__ deg) {
    int e = blockIdx.x*256 + threadIdx.x;
    if (e < EE) atomicAdd(&deg[dst[e]], ew[e]);
}

__global__ __launch_bounds__(256) void k_dinv(float* deg) {
    int n = blockIdx.x*256 + threadIdx.x;
    if (n < NTOT) deg[n] = rsqrtf(deg[n]);
}

// A[n,h] = x[n]*W1[h];  B[n,h] = dinv[n]^2 * A[n,h] + b1[h]   (self-loop folded in)
__global__ __launch_bounds__(256) void k_xw1(const float* __restrict__ x,
                                             const float* __restrict__ W1,
                                             const float* __restrict__ b1,
                                             const float* __restrict__ dinv,
                                             float* __restrict__ A,
                                             float* __restrict__ B) {
    int i = blockIdx.x*256 + threadIdx.x;     // over NTOT*16 float4s
    int n = i >> 4, q = i & 15;
    float xv = x[n];
    float di = dinv[n], d2 = di*di;
    float4 w  = ((const float4*)W1)[q];
    float4 bb = ((const float4*)b1)[q];
    float4 a;  a.x = xv*w.x;  a.y = xv*w.y;  a.z = xv*w.z;  a.w = xv*w.w;
    float4 b_; b_.x = d2*a.x + bb.x; b_.y = d2*a.y + bb.y;
               b_.z = d2*a.z + bb.z; b_.w = d2*a.w + bb.w;
    ((float4*)A)[i] = a;
    ((float4*)B)[i] = b_;
}

// B[dst,:] += dinv[src]*ew*dinv[dst] * A[src,:]   — 16 lanes per edge, float4 gather
__global__ __launch_bounds__(256) void k_scatter(const int* __restrict__ src,
                                                 const int* __restrict__ dst,
                                                 const float* __restrict__ ew,
                                                 const float* __restrict__ dinv,
                                                 const float* __restrict__ A,
                                                 float* __restrict__ B) {
    unsigned long long t = (unsigned long long)blockIdx.x*256ull + threadIdx.x;
    int e = (int)(t >> 4);
    if (e >= EE) return;
    int q = ((int)t & 15) << 2;
    int s = src[e], d = dst[e];
    float norm = dinv[s] * ew[e] * dinv[d];
    const float4 v = *(const float4*)(A + (size_t)s*64 + q);
    float* bp = B + (size_t)d*64 + q;
    atomicAdd(bp+0, norm*v.x);
    atomicAdd(bp+1, norm*v.y);
    atomicAdd(bp+2, norm*v.z);
    atomicAdd(bp+3, norm*v.w);
}

// GCN layer 2: y = relu(B-row); xw2 = y @ W2; A-row = xw2; B-row = dinv^2*xw2 + b2
// 64 nodes/block in LDS; thread (p,c): nodes {p, p+32}, outputs [c*8, c*8+8)
__global__ __launch_bounds__(256) void k_gcn2(float* __restrict__ A,
                                              float* __restrict__ B,
                                              const float* __restrict__ dinv,
                                              const float* __restrict__ W2,
                                              const float* __restrict__ b2) {
    __shared__ float ysh[64][68];
    int t = threadIdx.x;
    int n0 = blockIdx.x * 64;
    {   // cooperative load + relu: row r, quarter qq (16 floats)
        int r = t >> 2, qq = t & 3;
        const float4* bp = (const float4*)(B + (size_t)(n0 + r)*64 + qq*16);
        #pragma unroll
        for (int q = 0; q < 4; ++q) {
            float4 v = bp[q];
            v.x = fmaxf(v.x, 0.f); v.y = fmaxf(v.y, 0.f);
            v.z = fmaxf(v.z, 0.f); v.w = fmaxf(v.w, 0.f);
            ((float4*)&ysh[r][qq*16])[q] = v;
        }
    }
    __syncthreads();
    int p = t >> 3, c = t & 7;          // p: 0..31, c: 0..7
    int cb = c * 8;
    float4 a00 = {0,0,0,0}, a01 = {0,0,0,0};   // node p   : cols cb..cb+3, cb+4..cb+7
    float4 a10 = {0,0,0,0}, a11 = {0,0,0,0};   // node p+32
    #pragma unroll 8
    for (int k = 0; k < 64; ++k) {
        float y0 = ysh[p][k], y1 = ysh[p+32][k];
        float4 w0 = *(const float4*)(W2 + k*64 + cb);
        float4 w1 = *(const float4*)(W2 + k*64 + cb + 4);
        a00.x += y0*w0.x; a00.y += y0*w0.y; a00.z += y0*w0.z; a00.w += y0*w0.w;
        a01.x += y0*w1.x; a01.y += y0*w1.y; a01.z += y0*w1.z; a01.w += y0*w1.w;
        a10.x += y1*w0.x; a10.y += y1*w0.y; a10.z += y1*w0.z; a10.w += y1*w0.w;
        a11.x += y1*w1.x; a11.y += y1*w1.y; a11.z += y1*w1.z; a11.w += y1*w1.w;
    }
    float4 bb0 = *(const float4*)(b2 + cb);
    float4 bb1 = *(const float4*)(b2 + cb + 4);
    int nA = n0 + p, nB_ = n0 + p + 32;
    float dA = dinv[nA]; dA *= dA;
    float dB = dinv[nB_]; dB *= dB;
    *(float4*)(A + (size_t)nA*64 + cb)     = a00;
    *(float4*)(A + (size_t)nA*64 + cb + 4) = a01;
    *(float4*)(A + (size_t)nB_*64 + cb)     = a10;
    *(float4*)(A + (size_t)nB_*64 + cb + 4) = a11;
    float4 o;
    o.x = dA*a00.x + bb0.x; o.y = dA*a00.y + bb0.y; o.z = dA*a00.z + bb0.z; o.w = dA*a00.w + bb0.w;
    *(float4*)(B + (size_t)nA*64 + cb) = o;
    o.x = dA*a01.x + bb1.x; o.y = dA*a01.y + bb1.y; o.z = dA*a01.z + bb1.z; o.w = dA*a01.w + bb1.w;
    *(float4*)(B + (size_t)nA*64 + cb + 4) = o;
    o.x = dB*a10.x + bb0.x; o.y = dB*a10.y + bb0.y; o.z = dB*a10.z + bb0.z; o.w = dB*a10.w + bb0.w;
    *(float4*)(B + (size_t)nB_*64 + cb) = o;
    o.x = dB*a11.x + bb1.x; o.y = dB*a11.y + bb1.y; o.z = dB*a11.z + bb1.z; o.w = dB*a11.w + bb1.w;
    *(float4*)(B + (size_t)nB_*64 + cb + 4) = o;
}

// GRU + FC head. 64 nodes/block; thread (p,c): nodes {p, p+32}, gate rows l in [c*8, c*8+8).
// y/h tiles in LDS (read-only), hnew staged in osh and flushed coalesced.
__global__ __launch_bounds__(256) void k_gru(const float* __restrict__ B,
                                             const float* __restrict__ h_in,
                                             const float* __restrict__ wih,
                                             const float* __restrict__ whh,
                                             const float* __restrict__ bih,
                                             const float* __restrict__ bhh,
                                             const float* __restrict__ fcw,
                                             const float* __restrict__ fcb,
                                             float* __restrict__ out,
                                             float* __restrict__ hnew) {
    __shared__ float ysh[64][68];
    __shared__ float hsh[64][68];
    __shared__ float osh[64][68];
    int t = threadIdx.x;
    int n0 = blockIdx.x * 64;
    {
        int r = t >> 2, qq = t & 3;
        const float4* bp = (const float4*)(B + (size_t)(n0 + r)*64 + qq*16);
        const float4* hp = (const float4*)(h_in + (size_t)(n0 + r)*64 + qq*16);
        #pragma unroll
        for (int q = 0; q < 4; ++q) {
            float4 v = bp[q];
            v.x = fmaxf(v.x, 0.f); v.y = fmaxf(v.y, 0.f);
            v.z = fmaxf(v.z, 0.f); v.w = fmaxf(v.w, 0.f);
            ((float4*)&ysh[r][qq*16])[q] = v;
            ((float4*)&hsh[r][qq*16])[q] = hp[q];
        }
    }
    __syncthreads();
    int p = t >> 3, c = t & 7;          // p: 0..31, c: 0..7
    // 96 accumulators, all statically indexed (il loops fully unrolled)
    float ar0[8], az0[8], an0[8], gr0[8], gz0[8], gn0[8];
    float ar1[8], az1[8], an1[8], gr1[8], gz1[8], gn1[8];
    #pragma unroll
    for (int il = 0; il < 8; ++il) {
        ar0[il]=0.f; az0[il]=0.f; an0[il]=0.f; gr0[il]=0.f; gz0[il]=0.f; gn0[il]=0.f;
        ar1[il]=0.f; az1[il]=0.f; an1[il]=0.f; gr1[il]=0.f; gz1[il]=0.f; gn1[il]=0.f;
    }
    #pragma unroll 2
    for (int k4 = 0; k4 < 16; ++k4) {
        float4 y0 = *(const float4*)&ysh[p][k4*4];
        float4 y1 = *(const float4*)&ysh[p+32][k4*4];
        float4 h0 = *(const float4*)&hsh[p][k4*4];
        float4 h1 = *(const float4*)&hsh[p+32][k4*4];
        #pragma unroll
        for (int il = 0; il < 8; ++il) {
            int lg = c*8 + il;
            float4 wr = *(const float4*)(wih + (size_t)lg*64       + k4*4);
            float4 wz = *(const float4*)(wih + (size_t)(64+lg)*64  + k4*4);
            float4 wn = *(const float4*)(wih + (size_t)(128+lg)*64 + k4*4);
            float4 vr = *(const float4*)(whh + (size_t)lg*64       + k4*4);
            float4 vz = *(const float4*)(whh + (size_t)(64+lg)*64  + k4*4);
            float4 vn = *(const float4*)(whh + (size_t)(128+lg)*64 + k4*4);
            ar0[il] += dot4(y0, wr); az0[il] += dot4(y0, wz); an0[il] += dot4(y0, wn);
            gr0[il] += dot4(h0, vr); gz0[il] += dot4(h0, vz); gn0[il] += dot4(h0, vn);
            ar1[il] += dot4(y1, wr); az1[il] += dot4(y1, wz); an1[il] += dot4(y1, wn);
            gr1[il] += dot4(h1, vr); gz1[il] += dot4(h1, vz); gn1[il] += dot4(h1, vn);
        }
    }
    float po0[5], po1[5];
    #pragma unroll
    for (int j = 0; j < 5; ++j) { po0[j] = 0.f; po1[j] = 0.f; }
    #pragma unroll
    for (int il = 0; il < 8; ++il) {
        int lg = c*8 + il;
        float br = bih[lg], bz = bih[64+lg], bn = bih[128+lg];
        float cr = bhh[lg], cz = bhh[64+lg], cn = bhh[128+lg];
        // node p
        float r0 = sigm(ar0[il]+br + gr0[il]+cr);
        float z0 = sigm(az0[il]+bz + gz0[il]+cz);
        float nn0 = tanh_f(an0[il]+bn + r0*(gn0[il]+cn));
        float hf0 = hsh[p][lg];
        float hv0 = (1.f - z0)*nn0 + z0*hf0;
        osh[p][lg] = hv0;
        // node p+32
        float r1 = sigm(ar1[il]+br + gr1[il]+cr);
        float z1 = sigm(az1[il]+bz + gz1[il]+cz);
        float nn1 = tanh_f(an1[il]+bn + r1*(gn1[il]+cn));
        float hf1 = hsh[p+32][lg];
        float hv1 = (1.f - z1)*nn1 + z1*hf1;
        osh[p+32][lg] = hv1;
        #pragma unroll
        for (int j = 0; j < 5; ++j) {
            float fw = fcw[lg*5 + j];
            po0[j] += hv0*fw; po1[j] += hv1*fw;
        }
    }
    // FC reduction across the 8 c-lanes (contiguous lanes p*8+c)
    #pragma unroll
    for (int j = 0; j < 5; ++j) {
        #pragma unroll
        for (int m = 1; m < 8; m <<= 1) {
            po0[j] += __shfl_xor(po0[j], m);
            po1[j] += __shfl_xor(po1[j], m);
        }
    }
    if (c == 0) {
        #pragma unroll
        for (int j = 0; j < 5; ++j) {
            out[(size_t)(n0+p)*5 + j]    = po0[j] + fcb[j];
            out[(size_t)(n0+p+32)*5 + j] = po1[j] + fcb[j];
        }
    }
    __syncthreads();
    {   // coalesced full-line flush of hnew
        int r = t >> 2, qq = t & 3;
        float4* dp = (float4*)(hnew + (size_t)(n0 + r)*64 + qq*16);
        #pragma unroll
        for (int q = 0; q < 4; ++q) dp[q] = ((const float4*)&osh[r][qq*16])[q];
    }
}

extern "C" void kernel_launch(void* const* d_in, const int* in_sizes, int n_in,
                              void* d_out, int out_size, void* d_ws, size_t ws_size,
                              hipStream_t stream) {
    const float* x   = (const float*)d_in[0];
    const float* ew  = (const float*)d_in[1];
    const float* h   = (const float*)d_in[2];
    const float* W1  = (const float*)d_in[3];
    const float* b1  = (const float*)d_in[4];
    const float* W2  = (const float*)d_in[5];
    const float* b2  = (const float*)d_in[6];
    const float* wih = (const float*)d_in[7];
    const float* whh = (const float*)d_in[8];
    const float* bih = (const float*)d_in[9];
    const float* bhh = (const float*)d_in[10];
    const float* fcw = (const float*)d_in[11];
    const float* fcb = (const float*)d_in[12];
    const int*   ei  = (const int*)d_in[13];
    const int* src = ei;
    const int* dst = ei + EE;

    float* out  = (float*)d_out;
    // Reuse d_out's h_new region (N*64 floats) as the gather-source buffer A:
    // last read of A is scatter #2; k_gru then overwrites it with h_new.
    float* A    = out + (size_t)NTOT*5;
    float* dinv = (float*)d_ws;
    float* B    = (float*)((char*)d_ws + (1<<20));   // ws usage: 1MB + 51.2MB

    k_deg_init   <<<(NTOT+255)/256,    256, 0, stream>>>(dinv);
    k_deg_scatter<<<(EE+255)/256,      256, 0, stream>>>(ew, dst, dinv);
    k_dinv       <<<(NTOT+255)/256,    256, 0, stream>>>(dinv);
    k_xw1        <<<(NTOT*16)/256,     256, 0, stream>>>(x, W1, b1, dinv, A, B);
    k_scatter    <<<((EE*16)+255)/256, 256, 0, stream>>>(src, dst, ew, dinv, A, B);
    k_gcn2       <<<NTOT/64,           256, 0, stream>>>(A, B, dinv, W2, b2);
    k_scatter    <<<((EE*16)+255)/256, 256, 0, stream>>>(src, dst, ew, dinv, A, B);
    k_gru        <<<NTOT/64,           256, 0, stream>>>(B, h, wih, whh, bih, bhh,
                                                         fcw, fcb, out, A);
}

// Round 5
// 948.409 us; speedup vs baseline: 3.5815x; 3.5815x over previous
//
#include <hip/hip_runtime.h>

#define NTOT 200000
#define EE   1200000

typedef unsigned int u32;

__device__ __forceinline__ float rcpf(float x) { return __builtin_amdgcn_rcpf(x); }
__device__ __forceinline__ float sigm(float x) { return rcpf(1.f + __expf(-x)); }
__device__ __forceinline__ float tanh_f(float x) { return 1.f - 2.f * rcpf(__expf(2.f * x) + 1.f); }
__device__ __forceinline__ u32 f2bf(float f) {           // RNE f32->bf16
    u32 u = __float_as_uint(f);
    return (u + 0x7fffu + ((u >> 16) & 1u)) >> 16;
}
__device__ __forceinline__ float bf_lo(u32 p) { return __uint_as_float(p << 16); }
__device__ __forceinline__ float bf_hi(u32 p) { return __uint_as_float(p & 0xffff0000u); }

// ---------- degree / CSR build ----------
__global__ __launch_bounds__(256) void k_init(float* dinv, int* cnt) {
    int n = blockIdx.x*256 + threadIdx.x;
    if (n < NTOT) { dinv[n] = 1.0f; cnt[n] = 0; }
}

__global__ __launch_bounds__(256) void k_degcnt(const float* __restrict__ ew,
                                                const int* __restrict__ dst,
                                                float* __restrict__ deg,
                                                int* __restrict__ cnt) {
    int e = blockIdx.x*256 + threadIdx.x;
    if (e < EE) {
        int d = dst[e];
        atomicAdd(&deg[d], ew[e]);
        atomicAdd(&cnt[d], 1);
    }
}

__global__ __launch_bounds__(256) void k_dinv(float* deg) {
    int n = blockIdx.x*256 + threadIdx.x;
    if (n < NTOT) deg[n] = rsqrtf(deg[n]);
}

__global__ __launch_bounds__(256) void k_scan1(const int* __restrict__ cnt,
                                               int* __restrict__ off,
                                               int* __restrict__ bsum) {
    __shared__ int s[256];
    int t = threadIdx.x, i = blockIdx.x*256 + t;
    int v = (i < NTOT) ? cnt[i] : 0;
    s[t] = v; __syncthreads();
    #pragma unroll
    for (int o = 1; o < 256; o <<= 1) {
        int a = (t >= o) ? s[t-o] : 0; __syncthreads();
        s[t] += a; __syncthreads();
    }
    if (i < NTOT) off[i] = s[t] - v;          // block-local exclusive
    if (t == 255) bsum[blockIdx.x] = s[255];  // block total
}

__global__ __launch_bounds__(1024) void k_scan2(int* bsum) {   // 782 totals
    __shared__ int s[1024];
    int t = threadIdx.x;
    int v = (t < 782) ? bsum[t] : 0;
    s[t] = v; __syncthreads();
    for (int o = 1; o < 1024; o <<= 1) {
        int a = (t >= o) ? s[t-o] : 0; __syncthreads();
        s[t] += a; __syncthreads();
    }
    if (t < 782) bsum[t] = s[t] - v;          // exclusive
}

__global__ __launch_bounds__(256) void k_scan3(int* __restrict__ off,
                                               const int* __restrict__ bsum,
                                               int* __restrict__ cur) {
    int i = blockIdx.x*256 + threadIdx.x;
    if (i < NTOT) { int o = off[i] + bsum[blockIdx.x]; off[i] = o; cur[i] = o; }
    if (i == 0) off[NTOT] = EE;
}

__global__ __launch_bounds__(256) void k_fill(const int* __restrict__ dst,
                                              int* __restrict__ cur,
                                              int* __restrict__ eidx) {
    int e = blockIdx.x*256 + threadIdx.x;
    if (e < EE) { int p = atomicAdd(&cur[dst[e]], 1); eidx[p] = e; }
}

// ---------- layer 1 feature transform: A[n,h] = x[n]*W1[h] ----------
__global__ __launch_bounds__(256) void k_xw1(const float* __restrict__ x,
                                             const float* __restrict__ W1,
                                             float* __restrict__ A) {
    int i = blockIdx.x*256 + threadIdx.x;     // over NTOT*16 float4s
    int n = i >> 4, q = i & 15;
    float xv = x[n];
    float4 w = ((const float4*)W1)[q];
    float4 a; a.x = xv*w.x; a.y = xv*w.y; a.z = xv*w.z; a.w = xv*w.w;
    ((float4*)A)[i] = a;
}

// ---------- CSR gather: B[d,:] = relu( sum_e norm*A[src] + dinv^2*A[d] + bias ) ----------
__global__ __launch_bounds__(256) void k_gather(const float* __restrict__ A,
                                                const int* __restrict__ eidx,
                                                const int* __restrict__ off,
                                                const int* __restrict__ src,
                                                const float* __restrict__ ew,
                                                const float* __restrict__ dinv,
                                                const float* __restrict__ bias,
                                                float* __restrict__ B) {
    int wv = (blockIdx.x*256 + threadIdx.x) >> 6;   // wave index = node
    int lane = threadIdx.x & 63;
    if (wv >= NTOT) return;
    int e0 = off[wv], e1 = off[wv+1];
    float di = dinv[wv];
    float acc = di*di * A[(size_t)wv*64 + lane];
    for (int e = e0; e < e1; ++e) {
        int idx = eidx[e];
        int s = src[idx];
        float nrm = dinv[s] * ew[idx] * di;
        acc += nrm * A[(size_t)s*64 + lane];
    }
    B[(size_t)wv*64 + lane] = fmaxf(acc + bias[lane], 0.f);   // relu fused
}

// ---------- GCN layer 2 matmul: A = y1 @ W2  (y1 = B, already relu'd) ----------
__global__ __launch_bounds__(256) void k_gcn2(const float* __restrict__ B,
                                              float* __restrict__ A,
                                              const float* __restrict__ W2) {
    __shared__ float ysh[64][68];
    __shared__ u32 wsh[2048];                 // W2 [64][32] packed bf16 pairs
    int t = threadIdx.x;
    int n0 = blockIdx.x * 64;
    const float2* wf2 = (const float2*)W2;
    #pragma unroll
    for (int i = 0; i < 8; ++i) {
        int v = t + i*256;
        float2 w = wf2[v];
        wsh[v] = f2bf(w.x) | (f2bf(w.y) << 16);
    }
    {
        int r = t >> 2, qq = t & 3;
        const float4* bp = (const float4*)(B + (size_t)(n0 + r)*64 + qq*16);
        #pragma unroll
        for (int q = 0; q < 4; ++q) ((float4*)&ysh[r][qq*16])[q] = bp[q];
    }
    __syncthreads();
    int p = t >> 3, c = t & 7;
    const uint4* wq = (const uint4*)wsh;      // granule g = 8k + c  (conflict-free)
    float acc0[8], acc1[8];
    #pragma unroll
    for (int j = 0; j < 8; ++j) { acc0[j] = 0.f; acc1[j] = 0.f; }
    #pragma unroll 4
    for (int k = 0; k < 64; ++k) {
        float y0 = ysh[p][k], y1 = ysh[p+32][k];
        uint4 w = wq[8*k + c];
        float wv8[8] = { bf_lo(w.x), bf_hi(w.x), bf_lo(w.y), bf_hi(w.y),
                         bf_lo(w.z), bf_hi(w.z), bf_lo(w.w), bf_hi(w.w) };
        #pragma unroll
        for (int j = 0; j < 8; ++j) { acc0[j] += y0*wv8[j]; acc1[j] += y1*wv8[j]; }
    }
    int na = n0 + p, nb = n0 + p + 32, cb = c*8;
    float4 s0 = {acc0[0],acc0[1],acc0[2],acc0[3]};
    float4 s1 = {acc0[4],acc0[5],acc0[6],acc0[7]};
    float4 s2 = {acc1[0],acc1[1],acc1[2],acc1[3]};
    float4 s3 = {acc1[4],acc1[5],acc1[6],acc1[7]};
    *(float4*)(A + (size_t)na*64 + cb)     = s0;
    *(float4*)(A + (size_t)na*64 + cb + 4) = s1;
    *(float4*)(A + (size_t)nb*64 + cb)     = s2;
    *(float4*)(A + (size_t)nb*64 + cb + 4) = s3;
}

// ---------- GRU + FC head ----------
// 512 threads, 128 nodes/block. Weights bf16-packed in LDS, XOR-swizzled granules:
// granule(lg,k8) = k8*192 + (lg&~7) + ((lg&7) ^ ((lg>>3)&7)); read bank = 4*(il^c)+j -> conflict-free.
__global__ __launch_bounds__(512, 2) void k_gru(const float* B,
                                                const float* __restrict__ h_in,
                                                const float* __restrict__ wih,
                                                const float* __restrict__ whh,
                                                const float* __restrict__ bih,
                                                const float* __restrict__ bhh,
                                                const float* __restrict__ fcw,
                                                const float* __restrict__ fcb,
                                                float* __restrict__ out,
                                                float* hnew) {
    __shared__ u32 ihsh[6144];
    __shared__ u32 hhsh[6144];
    int t = threadIdx.x;
    int n0 = blockIdx.x * 128;
    const float2* ihf = (const float2*)wih;
    const float2* hhf = (const float2*)whh;
    #pragma unroll
    for (int i = 0; i < 12; ++i) {
        int v = t + i*512;                    // packed-pair index over [192][32]
        int lg = v >> 5, col = v & 31;
        int k8 = col >> 2, j = col & 3;
        int g = (k8*192 + (lg & ~7) + ((lg & 7) ^ ((lg >> 3) & 7)))*4 + j;
        float2 a = ihf[v]; float2 b = hhf[v];
        ihsh[g] = f2bf(a.x) | (f2bf(a.y) << 16);
        hhsh[g] = f2bf(b.x) | (f2bf(b.y) << 16);
    }
    __syncthreads();
    int p = t >> 3, c = t & 7;
    int na = n0 + p, nb = n0 + 64 + p;
    bool v1 = (nb < NTOT);
    const float* Br0 = B + (size_t)na*64;
    const float* Br1 = B + (v1 ? (size_t)nb*64 : 0);
    const float* Hr0 = h_in + (size_t)na*64;
    const float* Hr1 = h_in + (v1 ? (size_t)nb*64 : 0);

    float ar0[8], az0[8], an0[8], gr0[8], gz0[8], gn0[8];
    float ar1[8], az1[8], an1[8], gr1[8], gz1[8], gn1[8];
    #pragma unroll
    for (int il = 0; il < 8; ++il) {
        ar0[il]=0.f; az0[il]=0.f; an0[il]=0.f; gr0[il]=0.f; gz0[il]=0.f; gn0[il]=0.f;
        ar1[il]=0.f; az1[il]=0.f; an1[il]=0.f; gr1[il]=0.f; gz1[il]=0.f; gn1[il]=0.f;
    }
    const uint4* ihq = (const uint4*)ihsh;
    const uint4* hhq = (const uint4*)hhsh;
    #pragma unroll 1
    for (int k8 = 0; k8 < 8; ++k8) {
        float y0[8], y1[8], h0[8], h1[8];
        { const float4* pp = (const float4*)(Br0 + k8*8);
          *(float4*)&y0[0] = pp[0]; *(float4*)&y0[4] = pp[1]; }
        { const float4* pp = (const float4*)(Br1 + k8*8);
          *(float4*)&y1[0] = pp[0]; *(float4*)&y1[4] = pp[1]; }
        { const float4* pp = (const float4*)(Hr0 + k8*8);
          *(float4*)&h0[0] = pp[0]; *(float4*)&h0[4] = pp[1]; }
        { const float4* pp = (const float4*)(Hr1 + k8*8);
          *(float4*)&h1[0] = pp[0]; *(float4*)&h1[4] = pp[1]; }
        int gb = k8*192 + 8*c;
        #pragma unroll
        for (int il = 0; il < 8; ++il) {
            int g0 = gb + (il ^ c);
            uint4 wr = ihq[g0], wz = ihq[g0+64], wn = ihq[g0+128];
            uint4 vr = hhq[g0], vz = hhq[g0+64], vn = hhq[g0+128];
            float w;
            w=bf_lo(wr.x); ar0[il]+=y0[0]*w; ar1[il]+=y1[0]*w;
            w=bf_hi(wr.x); ar0[il]+=y0[1]*w; ar1[il]+=y1[1]*w;
            w=bf_lo(wr.y); ar0[il]+=y0[2]*w; ar1[il]+=y1[2]*w;
            w=bf_hi(wr.y); ar0[il]+=y0[3]*w; ar1[il]+=y1[3]*w;
            w=bf_lo(wr.z); ar0[il]+=y0[4]*w; ar1[il]+=y1[4]*w;
            w=bf_hi(wr.z); ar0[il]+=y0[5]*w; ar1[il]+=y1[5]*w;
            w=bf_lo(wr.w); ar0[il]+=y0[6]*w; ar1[il]+=y1[6]*w;
            w=bf_hi(wr.w); ar0[il]+=y0[7]*w; ar1[il]+=y1[7]*w;
            w=bf_lo(wz.x); az0[il]+=y0[0]*w; az1[il]+=y1[0]*w;
            w=bf_hi(wz.x); az0[il]+=y0[1]*w; az1[il]+=y1[1]*w;
            w=bf_lo(wz.y); az0[il]+=y0[2]*w; az1[il]+=y1[2]*w;
            w=bf_hi(wz.y); az0[il]+=y0[3]*w; az1[il]+=y1[3]*w;
            w=bf_lo(wz.z); az0[il]+=y0[4]*w; az1[il]+=y1[4]*w;
            w=bf_hi(wz.z); az0[il]+=y0[5]*w; az1[il]+=y1[5]*w;
            w=bf_lo(wz.w); az0[il]+=y0[6]*w; az1[il]+=y1[6]*w;
            w=bf_hi(wz.w); az0[il]+=y0[7]*w; az1[il]+=y1[7]*w;
            w=bf_lo(wn.x); an0[il]+=y0[0]*w; an1[il]+=y1[0]*w;
            w=bf_hi(wn.x); an0[il]+=y0[1]*w; an1[il]+=y1[1]*w;
            w=bf_lo(wn.y); an0[il]+=y0[2]*w; an1[il]+=y1[2]*w;
            w=bf_hi(wn.y); an0[il]+=y0[3]*w; an1[il]+=y1[3]*w;
            w=bf_lo(wn.z); an0[il]+=y0[4]*w; an1[il]+=y1[4]*w;
            w=bf_hi(wn.z); an0[il]+=y0[5]*w; an1[il]+=y1[5]*w;
            w=bf_lo(wn.w); an0[il]+=y0[6]*w; an1[il]+=y1[6]*w;
            w=bf_hi(wn.w); an0[il]+=y0[7]*w; an1[il]+=y1[7]*w;
            w=bf_lo(vr.x); gr0[il]+=h0[0]*w; gr1[il]+=h1[0]*w;
            w=bf_hi(vr.x); gr0[il]+=h0[1]*w; gr1[il]+=h1[1]*w;
            w=bf_lo(vr.y); gr0[il]+=h0[2]*w; gr1[il]+=h1[2]*w;
            w=bf_hi(vr.y); gr0[il]+=h0[3]*w; gr1[il]+=h1[3]*w;
            w=bf_lo(vr.z); gr0[il]+=h0[4]*w; gr1[il]+=h1[4]*w;
            w=bf_hi(vr.z); gr0[il]+=h0[5]*w; gr1[il]+=h1[5]*w;
            w=bf_lo(vr.w); gr0[il]+=h0[6]*w; gr1[il]+=h1[6]*w;
            w=bf_hi(vr.w); gr0[il]+=h0[7]*w; gr1[il]+=h1[7]*w;
            w=bf_lo(vz.x); gz0[il]+=h0[0]*w; gz1[il]+=h1[0]*w;
            w=bf_hi(vz.x); gz0[il]+=h0[1]*w; gz1[il]+=h1[1]*w;
            w=bf_lo(vz.y); gz0[il]+=h0[2]*w; gz1[il]+=h1[2]*w;
            w=bf_hi(vz.y); gz0[il]+=h0[3]*w; gz1[il]+=h1[3]*w;
            w=bf_lo(vz.z); gz0[il]+=h0[4]*w; gz1[il]+=h1[4]*w;
            w=bf_hi(vz.z); gz0[il]+=h0[5]*w; gz1[il]+=h1[5]*w;
            w=bf_lo(vz.w); gz0[il]+=h0[6]*w; gz1[il]+=h1[6]*w;
            w=bf_hi(vz.w); gz0[il]+=h0[7]*w; gz1[il]+=h1[7]*w;
            w=bf_lo(vn.x); gn0[il]+=h0[0]*w; gn1[il]+=h1[0]*w;
            w=bf_hi(vn.x); gn0[il]+=h0[1]*w; gn1[il]+=h1[1]*w;
            w=bf_lo(vn.y); gn0[il]+=h0[2]*w; gn1[il]+=h1[2]*w;
            w=bf_hi(vn.y); gn0[il]+=h0[3]*w; gn1[il]+=h1[3]*w;
            w=bf_lo(vn.z); gn0[il]+=h0[4]*w; gn1[il]+=h1[4]*w;
            w=bf_hi(vn.z); gn0[il]+=h0[5]*w; gn1[il]+=h1[5]*w;
            w=bf_lo(vn.w); gn0[il]+=h0[6]*w; gn1[il]+=h1[6]*w;
            w=bf_hi(vn.w); gn0[il]+=h0[7]*w; gn1[il]+=h1[7]*w;
        }
    }
    int cb = c*8;
    float hv0a[8], hv1a[8];
    float po0[5], po1[5];
    #pragma unroll
    for (int j = 0; j < 5; ++j) { po0[j] = 0.f; po1[j] = 0.f; }
    #pragma unroll
    for (int il = 0; il < 8; ++il) {
        int lg = cb + il;
        float br = bih[lg], bz = bih[64+lg], bn = bih[128+lg];
        float cr = bhh[lg], cz = bhh[64+lg], cn = bhh[128+lg];
        float r0 = sigm(ar0[il]+br + gr0[il]+cr);
        float z0 = sigm(az0[il]+bz + gz0[il]+cz);
        float q0 = tanh_f(an0[il]+bn + r0*(gn0[il]+cn));
        float hf0 = Hr0[lg];
        float hv0 = (1.f - z0)*q0 + z0*hf0;
        hv0a[il] = hv0;
        float r1 = sigm(ar1[il]+br + gr1[il]+cr);
        float z1 = sigm(az1[il]+bz + gz1[il]+cz);
        float q1 = tanh_f(an1[il]+bn + r1*(gn1[il]+cn));
        float hf1 = Hr1[lg];
        float hv1 = (1.f - z1)*q1 + z1*hf1;
        hv1a[il] = hv1;
        #pragma unroll
        for (int j = 0; j < 5; ++j) {
            float fw = fcw[lg*5 + j];
            po0[j] += hv0*fw; po1[j] += hv1*fw;
        }
    }
    // hnew stores (coalesced across the 8 c-lanes of each row)
    float4 hA0 = {hv0a[0],hv0a[1],hv0a[2],hv0a[3]};
    float4 hA1 = {hv0a[4],hv0a[5],hv0a[6],hv0a[7]};
    *(float4*)(hnew + (size_t)na*64 + cb)     = hA0;
    *(float4*)(hnew + (size_t)na*64 + cb + 4) = hA1;
    if (v1) {
        float4 hB0 = {hv1a[0],hv1a[1],hv1a[2],hv1a[3]};
        float4 hB1 = {hv1a[4],hv1a[5],hv1a[6],hv1a[7]};
        *(float4*)(hnew + (size_t)nb*64 + cb)     = hB0;
        *(float4*)(hnew + (size_t)nb*64 + cb + 4) = hB1;
    }
    // FC head: reduce over the 8 c-lanes
    #pragma unroll
    for (int j = 0; j < 5; ++j) {
        #pragma unroll
        for (int m = 1; m < 8; m <<= 1) {
            po0[j] += __shfl_xor(po0[j], m);
            po1[j] += __shfl_xor(po1[j], m);
        }
    }
    if (c == 0) {
        #pragma unroll
        for (int j = 0; j < 5; ++j) out[(size_t)na*5 + j] = po0[j] + fcb[j];
        if (v1) {
            #pragma unroll
            for (int j = 0; j < 5; ++j) out[(size_t)nb*5 + j] = po1[j] + fcb[j];
        }
    }
}

extern "C" void kernel_launch(void* const* d_in, const int* in_sizes, int n_in,
                              void* d_out, int out_size, void* d_ws, size_t ws_size,
                              hipStream_t stream) {
    const float* x   = (const float*)d_in[0];
    const float* ew  = (const float*)d_in[1];
    const float* h   = (const float*)d_in[2];
    const float* W1  = (const float*)d_in[3];
    const float* b1  = (const float*)d_in[4];
    const float* W2  = (const float*)d_in[5];
    const float* b2  = (const float*)d_in[6];
    const float* wih = (const float*)d_in[7];
    const float* whh = (const float*)d_in[8];
    const float* bih = (const float*)d_in[9];
    const float* bhh = (const float*)d_in[10];
    const float* fcw = (const float*)d_in[11];
    const float* fcb = (const float*)d_in[12];
    const int*   ei  = (const int*)d_in[13];
    const int* src = ei;
    const int* dst = ei + EE;

    // ws layout: dinv @0 (0.8MB) | A @1MiB (51.2MB) | eidx @50MiB (4.8MB)
    float* dinv = (float*)d_ws;
    float* A    = (float*)((char*)d_ws + (1<<20));
    int*   eidx = (int*)((char*)d_ws + 52428800);
    // d_out head (4MB, dead until k_gru's final out-write) hosts CSR ints
    int*   cnt  = (int*)d_out;          // 200000 (later reused as fill cursor)
    int*   off  = cnt + NTOT;           // 200001
    int*   bsum = off + NTOT + 1;       // 782
    float* out  = (float*)d_out;
    float* Bbuf = out + (size_t)NTOT*5; // d_out tail: B buffer, finally hnew

    k_init  <<<782,   256, 0, stream>>>(dinv, cnt);
    k_degcnt<<<4688,  256, 0, stream>>>(ew, dst, dinv, cnt);
    k_dinv  <<<782,   256, 0, stream>>>(dinv);
    k_scan1 <<<782,   256, 0, stream>>>(cnt, off, bsum);
    k_scan2 <<<1,    1024, 0, stream>>>(bsum);
    k_scan3 <<<782,   256, 0, stream>>>(off, bsum, cnt);
    k_fill  <<<4688,  256, 0, stream>>>(dst, cnt, eidx);
    k_xw1   <<<12500, 256, 0, stream>>>(x, W1, A);
    k_gather<<<50000, 256, 0, stream>>>(A, eidx, off, src, ew, dinv, b1, Bbuf);
    k_gcn2  <<<3125,  256, 0, stream>>>(Bbuf, A, W2);
    k_gather<<<50000, 256, 0, stream>>>(A, eidx, off, src, ew, dinv, b2, Bbuf);
    k_gru   <<<1563,  512, 0, stream>>>(Bbuf, h, wih, whh, bih, bhh,
                                        fcw, fcb, out, Bbuf);
}

// Round 8
// 739.556 us; speedup vs baseline: 4.5929x; 1.2824x over previous
//
#include <hip/hip_runtime.h>

#define NTOT 200000
#define EE   1200000

typedef unsigned int u32;

__device__ __forceinline__ float rcpf(float x) { return __builtin_amdgcn_rcpf(x); }
__device__ __forceinline__ float sigm(float x) { return rcpf(1.f + __expf(-x)); }
__device__ __forceinline__ float tanh_f(float x) { return 1.f - 2.f * rcpf(__expf(2.f * x) + 1.f); }
__device__ __forceinline__ u32 f2bf(float f) {           // RNE f32->bf16
    u32 u = __float_as_uint(f);
    return (u + 0x7fffu + ((u >> 16) & 1u)) >> 16;
}
__device__ __forceinline__ float bf_lo(u32 p) { return __uint_as_float(p << 16); }
__device__ __forceinline__ float bf_hi(u32 p) { return __uint_as_float(p & 0xffff0000u); }

// ---------- CSR build ----------
__global__ __launch_bounds__(256) void k_init(int* cnt) {
    int n = blockIdx.x*256 + threadIdx.x;
    if (n < NTOT) cnt[n] = 0;
}

__global__ __launch_bounds__(256) void k_cnt(const int* __restrict__ dst,
                                             int* __restrict__ cnt) {
    int e = blockIdx.x*256 + threadIdx.x;
    if (e < EE) atomicAdd(&cnt[dst[e]], 1);
}

__global__ __launch_bounds__(256) void k_scan1(const int* __restrict__ cnt,
                                               int* __restrict__ off,
                                               int* __restrict__ bsum) {
    __shared__ int s[256];
    int t = threadIdx.x, i = blockIdx.x*256 + t;
    int v = (i < NTOT) ? cnt[i] : 0;
    s[t] = v; __syncthreads();
    #pragma unroll
    for (int o = 1; o < 256; o <<= 1) {
        int a = (t >= o) ? s[t-o] : 0; __syncthreads();
        s[t] += a; __syncthreads();
    }
    if (i < NTOT) off[i] = s[t] - v;
    if (t == 255) bsum[blockIdx.x] = s[255];
}

__global__ __launch_bounds__(1024) void k_scan2(int* bsum) {   // 782 totals
    __shared__ int s[1024];
    int t = threadIdx.x;
    int v = (t < 782) ? bsum[t] : 0;
    s[t] = v; __syncthreads();
    for (int o = 1; o < 1024; o <<= 1) {
        int a = (t >= o) ? s[t-o] : 0; __syncthreads();
        s[t] += a; __syncthreads();
    }
    if (t < 782) bsum[t] = s[t] - v;
}

__global__ __launch_bounds__(256) void k_scan3(int* __restrict__ off,
                                               const int* __restrict__ bsum,
                                               int* __restrict__ cur) {
    int i = blockIdx.x*256 + threadIdx.x;
    if (i < NTOT) { int o = off[i] + bsum[blockIdx.x]; off[i] = o; cur[i] = o; }
    if (i == 0) off[NTOT] = EE;
}

__global__ __launch_bounds__(256) void k_fill(const int* __restrict__ dst,
                                              int* __restrict__ cur,
                                              int* __restrict__ eidx) {
    int e = blockIdx.x*256 + threadIdx.x;
    if (e < EE) { int p = atomicAdd(&cur[dst[e]], 1); eidx[p] = e; }
}

// deg via CSR (no float atomics): deg = 1 + sum(ew); dinv = rsqrt
__global__ __launch_bounds__(256) void k_deg(const int* __restrict__ off,
                                             const int* __restrict__ eidx,
                                             const float* __restrict__ ew,
                                             float* __restrict__ dinv) {
    int n = blockIdx.x*256 + threadIdx.x;
    if (n >= NTOT) return;
    int e0 = off[n], e1 = off[n+1];
    float dg = 1.f;
    for (int e = e0; e < e1; ++e) dg += ew[eidx[e]];
    dinv[n] = rsqrtf(dg);
}

// layer-1 scalar aggregation (T=1 rank-1 trick):
// sagg[n] = dinv[n]*sum_e dinv[src]*ew*x[src] + dinv[n]^2*x[n]
__global__ __launch_bounds__(256) void k_sagg(const int* __restrict__ off,
                                              const int* __restrict__ eidx,
                                              const int* __restrict__ src,
                                              const float* __restrict__ ew,
                                              const float* __restrict__ x,
                                              const float* __restrict__ dinv,
                                              float* __restrict__ sagg) {
    int n = blockIdx.x*256 + threadIdx.x;
    if (n >= NTOT) return;
    int e0 = off[n], e1 = off[n+1];
    float s = 0.f;
    for (int e = e0; e < e1; ++e) {
        int idx = eidx[e];
        int sr = src[idx];
        s += dinv[sr]*ew[idx]*x[sr];
    }
    float di = dinv[n];
    sagg[n] = di*s + di*di*x[n];
}

// fused: y1 = relu(sagg*W1 + b1)  ->  A2 = y1 @ W2   (W2 f32 in LDS)
__global__ __launch_bounds__(256) void k_l12(const float* __restrict__ sagg,
                                             const float* __restrict__ W1,
                                             const float* __restrict__ b1,
                                             const float* __restrict__ W2,
                                             float* __restrict__ A2) {
    __shared__ float ysh[64][68];
    __shared__ float wsh[64*68];              // W2 row k at k*68, f32
    int t = threadIdx.x;
    int n0 = blockIdx.x * 64;
    #pragma unroll
    for (int i = 0; i < 16; ++i) {
        int v = t + i*256;                    // coalesced global read of W2
        wsh[(v >> 6)*68 + (v & 63)] = W2[v];
    }
    {
        int row = t >> 2, c0 = (t & 3) * 16;
        float sv = sagg[n0 + row];
        #pragma unroll
        for (int q = 0; q < 4; ++q) {
            float4 w  = *(const float4*)(W1 + c0 + q*4);
            float4 bb = *(const float4*)(b1 + c0 + q*4);
            ysh[row][c0+q*4+0] = fmaxf(sv*w.x + bb.x, 0.f);
            ysh[row][c0+q*4+1] = fmaxf(sv*w.y + bb.y, 0.f);
            ysh[row][c0+q*4+2] = fmaxf(sv*w.z + bb.z, 0.f);
            ysh[row][c0+q*4+3] = fmaxf(sv*w.w + bb.w, 0.f);
        }
    }
    __syncthreads();
    int p = t >> 3, c = t & 7;
    float acc0[8], acc1[8];
    #pragma unroll
    for (int j = 0; j < 8; ++j) { acc0[j] = 0.f; acc1[j] = 0.f; }
    #pragma unroll 4
    for (int k = 0; k < 64; ++k) {
        float y0 = ysh[p][k], y1 = ysh[p+32][k];
        const float* wr = wsh + k*68 + c*8;
        float4 w0 = *(const float4*)wr;
        float4 w1 = *(const float4*)(wr + 4);
        acc0[0] += y0*w0.x; acc0[1] += y0*w0.y; acc0[2] += y0*w0.z; acc0[3] += y0*w0.w;
        acc0[4] += y0*w1.x; acc0[5] += y0*w1.y; acc0[6] += y0*w1.z; acc0[7] += y0*w1.w;
        acc1[0] += y1*w0.x; acc1[1] += y1*w0.y; acc1[2] += y1*w0.z; acc1[3] += y1*w0.w;
        acc1[4] += y1*w1.x; acc1[5] += y1*w1.y; acc1[6] += y1*w1.z; acc1[7] += y1*w1.w;
    }
    int na = n0 + p, nb = n0 + p + 32, cb = c*8;
    float4 s0 = {acc0[0],acc0[1],acc0[2],acc0[3]};
    float4 s1 = {acc0[4],acc0[5],acc0[6],acc0[7]};
    float4 s2 = {acc1[0],acc1[1],acc1[2],acc1[3]};
    float4 s3 = {acc1[4],acc1[5],acc1[6],acc1[7]};
    *(float4*)(A2 + (size_t)na*64 + cb)     = s0;
    *(float4*)(A2 + (size_t)na*64 + cb + 4) = s1;
    *(float4*)(A2 + (size_t)nb*64 + cb)     = s2;
    *(float4*)(A2 + (size_t)nb*64 + cb + 4) = s3;
}

// CSR vector gather (layer 2): B2[d,:] = relu(sum norm*A2[src] + dinv^2*A2[d] + b2)
__global__ __launch_bounds__(256) void k_gather(const float* __restrict__ A,
                                                const int* __restrict__ eidx,
                                                const int* __restrict__ off,
                                                const int* __restrict__ src,
                                                const float* __restrict__ ew,
                                                const float* __restrict__ dinv,
                                                const float* __restrict__ bias,
                                                float* __restrict__ B) {
    int wv = (blockIdx.x*256 + threadIdx.x) >> 6;   // wave index = node
    int lane = threadIdx.x & 63;
    if (wv >= NTOT) return;
    int e0 = off[wv], e1 = off[wv+1];
    float di = dinv[wv];
    float acc = di*di * A[(size_t)wv*64 + lane];
    for (int e = e0; e < e1; ++e) {
        int idx = eidx[e];
        int s = src[idx];
        float nrm = dinv[s] * ew[idx] * di;
        acc += nrm * A[(size_t)s*64 + lane];
    }
    B[(size_t)wv*64 + lane] = fmaxf(acc + bias[lane], 0.f);
}

// ---------- GRU + FC head (round-4 proven VALU version) ----------
// 512 threads, 128 nodes/block. Weights bf16-packed in LDS, XOR-swizzled granules:
// granule(lg,k8) = k8*192 + (lg&~7) + ((lg&7) ^ ((lg>>3)&7)); read bank = 4*(il^c)+j -> conflict-free.
__global__ __launch_bounds__(512, 2) void k_gru(const float* B,
                                                const float* __restrict__ h_in,
                                                const float* __restrict__ wih,
                                                const float* __restrict__ whh,
                                                const float* __restrict__ bih,
                                                const float* __restrict__ bhh,
                                                const float* __restrict__ fcw,
                                                const float* __restrict__ fcb,
                                                float* __restrict__ out,
                                                float* hnew) {
    __shared__ u32 ihsh[6144];
    __shared__ u32 hhsh[6144];
    int t = threadIdx.x;
    int n0 = blockIdx.x * 128;
    const float2* ihf = (const float2*)wih;
    const float2* hhf = (const float2*)whh;
    #pragma unroll
    for (int i = 0; i < 12; ++i) {
        int v = t + i*512;                    // packed-pair index over [192][32]
        int lg = v >> 5, col = v & 31;
        int k8 = col >> 2, j = col & 3;
        int g = (k8*192 + (lg & ~7) + ((lg & 7) ^ ((lg >> 3) & 7)))*4 + j;
        float2 a = ihf[v]; float2 b = hhf[v];
        ihsh[g] = f2bf(a.x) | (f2bf(a.y) << 16);
        hhsh[g] = f2bf(b.x) | (f2bf(b.y) << 16);
    }
    __syncthreads();
    int p = t >> 3, c = t & 7;
    int na = n0 + p, nb = n0 + 64 + p;
    bool v1 = (nb < NTOT);
    const float* Br0 = B + (size_t)na*64;
    const float* Br1 = B + (v1 ? (size_t)nb*64 : 0);
    const float* Hr0 = h_in + (size_t)na*64;
    const float* Hr1 = h_in + (v1 ? (size_t)nb*64 : 0);

    float ar0[8], az0[8], an0[8], gr0[8], gz0[8], gn0[8];
    float ar1[8], az1[8], an1[8], gr1[8], gz1[8], gn1[8];
    #pragma unroll
    for (int il = 0; il < 8; ++il) {
        ar0[il]=0.f; az0[il]=0.f; an0[il]=0.f; gr0[il]=0.f; gz0[il]=0.f; gn0[il]=0.f;
        ar1[il]=0.f; az1[il]=0.f; an1[il]=0.f; gr1[il]=0.f; gz1[il]=0.f; gn1[il]=0.f;
    }
    const uint4* ihq = (const uint4*)ihsh;
    const uint4* hhq = (const uint4*)hhsh;
    #pragma unroll 1
    for (int k8 = 0; k8 < 8; ++k8) {
        float y0[8], y1[8], h0[8], h1[8];
        { const float4* pp = (const float4*)(Br0 + k8*8);
          *(float4*)&y0[0] = pp[0]; *(float4*)&y0[4] = pp[1]; }
        { const float4* pp = (const float4*)(Br1 + k8*8);
          *(float4*)&y1[0] = pp[0]; *(float4*)&y1[4] = pp[1]; }
        { const float4* pp = (const float4*)(Hr0 + k8*8);
          *(float4*)&h0[0] = pp[0]; *(float4*)&h0[4] = pp[1]; }
        { const float4* pp = (const float4*)(Hr1 + k8*8);
          *(float4*)&h1[0] = pp[0]; *(float4*)&h1[4] = pp[1]; }
        int gb = k8*192 + 8*c;
        #pragma unroll
        for (int il = 0; il < 8; ++il) {
            int g0 = gb + (il ^ c);
            uint4 wr = ihq[g0], wz = ihq[g0+64], wn = ihq[g0+128];
            uint4 vr = hhq[g0], vz = hhq[g0+64], vn = hhq[g0+128];
            float w;
            w=bf_lo(wr.x); ar0[il]+=y0[0]*w; ar1[il]+=y1[0]*w;
            w=bf_hi(wr.x); ar0[il]+=y0[1]*w; ar1[il]+=y1[1]*w;
            w=bf_lo(wr.y); ar0[il]+=y0[2]*w; ar1[il]+=y1[2]*w;
            w=bf_hi(wr.y); ar0[il]+=y0[3]*w; ar1[il]+=y1[3]*w;
            w=bf_lo(wr.z); ar0[il]+=y0[4]*w; ar1[il]+=y1[4]*w;
            w=bf_hi(wr.z); ar0[il]+=y0[5]*w; ar1[il]+=y1[5]*w;
            w=bf_lo(wr.w); ar0[il]+=y0[6]*w; ar1[il]+=y1[6]*w;
            w=bf_hi(wr.w); ar0[il]+=y0[7]*w; ar1[il]+=y1[7]*w;
            w=bf_lo(wz.x); az0[il]+=y0[0]*w; az1[il]+=y1[0]*w;
            w=bf_hi(wz.x); az0[il]+=y0[1]*w; az1[il]+=y1[1]*w;
            w=bf_lo(wz.y); az0[il]+=y0[2]*w; az1[il]+=y1[2]*w;
            w=bf_hi(wz.y); az0[il]+=y0[3]*w; az1[il]+=y1[3]*w;
            w=bf_lo(wz.z); az0[il]+=y0[4]*w; az1[il]+=y1[4]*w;
            w=bf_hi(wz.z); az0[il]+=y0[5]*w; az1[il]+=y1[5]*w;
            w=bf_lo(wz.w); az0[il]+=y0[6]*w; az1[il]+=y1[6]*w;
            w=bf_hi(wz.w); az0[il]+=y0[7]*w; az1[il]+=y1[7]*w;
            w=bf_lo(wn.x); an0[il]+=y0[0]*w; an1[il]+=y1[0]*w;
            w=bf_hi(wn.x); an0[il]+=y0[1]*w; an1[il]+=y1[1]*w;
            w=bf_lo(wn.y); an0[il]+=y0[2]*w; an1[il]+=y1[2]*w;
            w=bf_hi(wn.y); an0[il]+=y0[3]*w; an1[il]+=y1[3]*w;
            w=bf_lo(wn.z); an0[il]+=y0[4]*w; an1[il]+=y1[4]*w;
            w=bf_hi(wn.z); an0[il]+=y0[5]*w; an1[il]+=y1[5]*w;
            w=bf_lo(wn.w); an0[il]+=y0[6]*w; an1[il]+=y1[6]*w;
            w=bf_hi(wn.w); an0[il]+=y0[7]*w; an1[il]+=y1[7]*w;
            w=bf_lo(vr.x); gr0[il]+=h0[0]*w; gr1[il]+=h1[0]*w;
            w=bf_hi(vr.x); gr0[il]+=h0[1]*w; gr1[il]+=h1[1]*w;
            w=bf_lo(vr.y); gr0[il]+=h0[2]*w; gr1[il]+=h1[2]*w;
            w=bf_hi(vr.y); gr0[il]+=h0[3]*w; gr1[il]+=h1[3]*w;
            w=bf_lo(vr.z); gr0[il]+=h0[4]*w; gr1[il]+=h1[4]*w;
            w=bf_hi(vr.z); gr0[il]+=h0[5]*w; gr1[il]+=h1[5]*w;
            w=bf_lo(vr.w); gr0[il]+=h0[6]*w; gr1[il]+=h1[6]*w;
            w=bf_hi(vr.w); gr0[il]+=h0[7]*w; gr1[il]+=h1[7]*w;
            w=bf_lo(vz.x); gz0[il]+=h0[0]*w; gz1[il]+=h1[0]*w;
            w=bf_hi(vz.x); gz0[il]+=h0[1]*w; gz1[il]+=h1[1]*w;
            w=bf_lo(vz.y); gz0[il]+=h0[2]*w; gz1[il]+=h1[2]*w;
            w=bf_hi(vz.y); gz0[il]+=h0[3]*w; gz1[il]+=h1[3]*w;
            w=bf_lo(vz.z); gz0[il]+=h0[4]*w; gz1[il]+=h1[4]*w;
            w=bf_hi(vz.z); gz0[il]+=h0[5]*w; gz1[il]+=h1[5]*w;
            w=bf_lo(vz.w); gz0[il]+=h0[6]*w; gz1[il]+=h1[6]*w;
            w=bf_hi(vz.w); gz0[il]+=h0[7]*w; gz1[il]+=h1[7]*w;
            w=bf_lo(vn.x); gn0[il]+=h0[0]*w; gn1[il]+=h1[0]*w;
            w=bf_hi(vn.x); gn0[il]+=h0[1]*w; gn1[il]+=h1[1]*w;
            w=bf_lo(vn.y); gn0[il]+=h0[2]*w; gn1[il]+=h1[2]*w;
            w=bf_hi(vn.y); gn0[il]+=h0[3]*w; gn1[il]+=h1[3]*w;
            w=bf_lo(vn.z); gn0[il]+=h0[4]*w; gn1[il]+=h1[4]*w;
            w=bf_hi(vn.z); gn0[il]+=h0[5]*w; gn1[il]+=h1[5]*w;
            w=bf_lo(vn.w); gn0[il]+=h0[6]*w; gn1[il]+=h1[6]*w;
            w=bf_hi(vn.w); gn0[il]+=h0[7]*w; gn1[il]+=h1[7]*w;
        }
    }
    int cb = c*8;
    float hv0a[8], hv1a[8];
    float po0[5], po1[5];
    #pragma unroll
    for (int j = 0; j < 5; ++j) { po0[j] = 0.f; po1[j] = 0.f; }
    #pragma unroll
    for (int il = 0; il < 8; ++il) {
        int lg = cb + il;
        float br = bih[lg], bz = bih[64+lg], bn = bih[128+lg];
        float cr = bhh[lg], cz = bhh[64+lg], cn = bhh[128+lg];
        float r0 = sigm(ar0[il]+br + gr0[il]+cr);
        float z0 = sigm(az0[il]+bz + gz0[il]+cz);
        float q0 = tanh_f(an0[il]+bn + r0*(gn0[il]+cn));
        float hf0 = Hr0[lg];
        float hv0 = (1.f - z0)*q0 + z0*hf0;
        hv0a[il] = hv0;
        float r1 = sigm(ar1[il]+br + gr1[il]+cr);
        float z1 = sigm(az1[il]+bz + gz1[il]+cz);
        float q1 = tanh_f(an1[il]+bn + r1*(gn1[il]+cn));
        float hf1 = Hr1[lg];
        float hv1 = (1.f - z1)*q1 + z1*hf1;
        hv1a[il] = hv1;
        #pragma unroll
        for (int j = 0; j < 5; ++j) {
            float fw = fcw[lg*5 + j];
            po0[j] += hv0*fw; po1[j] += hv1*fw;
        }
    }
    // hnew stores (coalesced across the 8 c-lanes of each row)
    float4 hA0 = {hv0a[0],hv0a[1],hv0a[2],hv0a[3]};
    float4 hA1 = {hv0a[4],hv0a[5],hv0a[6],hv0a[7]};
    *(float4*)(hnew + (size_t)na*64 + cb)     = hA0;
    *(float4*)(hnew + (size_t)na*64 + cb + 4) = hA1;
    if (v1) {
        float4 hB0 = {hv1a[0],hv1a[1],hv1a[2],hv1a[3]};
        float4 hB1 = {hv1a[4],hv1a[5],hv1a[6],hv1a[7]};
        *(float4*)(hnew + (size_t)nb*64 + cb)     = hB0;
        *(float4*)(hnew + (size_t)nb*64 + cb + 4) = hB1;
    }
    // FC head: reduce over the 8 c-lanes
    #pragma unroll
    for (int j = 0; j < 5; ++j) {
        #pragma unroll
        for (int m = 1; m < 8; m <<= 1) {
            po0[j] += __shfl_xor(po0[j], m);
            po1[j] += __shfl_xor(po1[j], m);
        }
    }
    if (c == 0) {
        #pragma unroll
        for (int j = 0; j < 5; ++j) out[(size_t)na*5 + j] = po0[j] + fcb[j];
        if (v1) {
            #pragma unroll
            for (int j = 0; j < 5; ++j) out[(size_t)nb*5 + j] = po1[j] + fcb[j];
        }
    }
}

extern "C" void kernel_launch(void* const* d_in, const int* in_sizes, int n_in,
                              void* d_out, int out_size, void* d_ws, size_t ws_size,
                              hipStream_t stream) {
    const float* x   = (const float*)d_in[0];
    const float* ew  = (const float*)d_in[1];
    const float* h   = (const float*)d_in[2];
    const float* W1  = (const float*)d_in[3];
    const float* b1  = (const float*)d_in[4];
    const float* W2  = (const float*)d_in[5];
    const float* b2  = (const float*)d_in[6];
    const float* wih = (const float*)d_in[7];
    const float* whh = (const float*)d_in[8];
    const float* bih = (const float*)d_in[9];
    const float* bhh = (const float*)d_in[10];
    const float* fcw = (const float*)d_in[11];
    const float* fcb = (const float*)d_in[12];
    const int*   ei  = (const int*)d_in[13];
    const int* src = ei;
    const int* dst = ei + EE;

    // ws: A2 @0 (51.2MB) | eidx @51.2MB (4.8MB)
    float* A2    = (float*)d_ws;
    int*   eidx  = (int*)((char*)d_ws + 51200000);
    // d_out head (first NTOT*5 floats, dead until k_gru epilogue) hosts CSR + scalars
    int*   cnt  = (int*)d_out;                    // 200000, reused as fill cursor
    int*   off  = cnt + NTOT;                     // 200001
    int*   bsum = off + NTOT + 1;                 // 782
    float* dinv = (float*)d_out + 401024;
    float* sagg = (float*)d_out + 601024;
    float* out  = (float*)d_out;
    float* B2   = out + (size_t)NTOT*5;           // d_out tail: y2 buffer, finally hnew

    k_init  <<<782,   256, 0, stream>>>(cnt);
    k_cnt   <<<4688,  256, 0, stream>>>(dst, cnt);
    k_scan1 <<<782,   256, 0, stream>>>(cnt, off, bsum);
    k_scan2 <<<1,    1024, 0, stream>>>(bsum);
    k_scan3 <<<782,   256, 0, stream>>>(off, bsum, cnt);
    k_fill  <<<4688,  256, 0, stream>>>(dst, cnt, eidx);
    k_deg   <<<782,   256, 0, stream>>>(off, eidx, ew, dinv);
    k_sagg  <<<782,   256, 0, stream>>>(off, eidx, src, ew, x, dinv, sagg);
    k_l12   <<<3125,  256, 0, stream>>>(sagg, W1, b1, W2, A2);
    k_gather<<<50000, 256, 0, stream>>>(A2, eidx, off, src, ew, dinv, b2, B2);
    k_gru   <<<1563,  512, 0, stream>>>(B2, h, wih, whh, bih, bhh,
                                        fcw, fcb, out, B2);
}

// Round 9
// 514.676 us; speedup vs baseline: 6.5997x; 1.4369x over previous
//
#include <hip/hip_runtime.h>

#define NTOT 200000
#define EE   1200000

typedef unsigned int u32;
typedef __attribute__((ext_vector_type(8))) short short8v;
typedef __attribute__((ext_vector_type(4))) float f32x4;

__device__ __forceinline__ float rcpf(float x) { return __builtin_amdgcn_rcpf(x); }
__device__ __forceinline__ float sigm(float x) { return rcpf(1.f + __expf(-x)); }
__device__ __forceinline__ float tanh_f(float x) { return 1.f - 2.f * rcpf(__expf(2.f * x) + 1.f); }
__device__ __forceinline__ u32 f2bf(float f) {           // RNE f32->bf16
    u32 u = __float_as_uint(f);
    return (u + 0x7fffu + ((u >> 16) & 1u)) >> 16;
}
__device__ __forceinline__ float bf2f(u32 b) { return __uint_as_float(b << 16); }

__device__ __forceinline__ short8v packhi8(const float* v) {
    union { u32 u[4]; short8v s; } r;
    r.u[0] = f2bf(v[0]) | (f2bf(v[1]) << 16);
    r.u[1] = f2bf(v[2]) | (f2bf(v[3]) << 16);
    r.u[2] = f2bf(v[4]) | (f2bf(v[5]) << 16);
    r.u[3] = f2bf(v[6]) | (f2bf(v[7]) << 16);
    return r.s;
}
__device__ __forceinline__ short8v packlo8(const float* v) {
    float q[8];
    #pragma unroll
    for (int i = 0; i < 8; ++i) q[i] = v[i] - bf2f(f2bf(v[i]));
    union { u32 u[4]; short8v s; } r;
    r.u[0] = f2bf(q[0]) | (f2bf(q[1]) << 16);
    r.u[1] = f2bf(q[2]) | (f2bf(q[3]) << 16);
    r.u[2] = f2bf(q[4]) | (f2bf(q[5]) << 16);
    r.u[3] = f2bf(q[6]) | (f2bf(q[7]) << 16);
    return r.s;
}

// ---------- CSR build ----------
__global__ __launch_bounds__(256) void k_init(int* cnt) {
    int n = blockIdx.x*256 + threadIdx.x;
    if (n < NTOT) cnt[n] = 0;
}

__global__ __launch_bounds__(256) void k_cnt(const int* __restrict__ dst,
                                             int* __restrict__ cnt) {
    int e = blockIdx.x*256 + threadIdx.x;
    if (e < EE) atomicAdd(&cnt[dst[e]], 1);
}

__global__ __launch_bounds__(256) void k_scan1(const int* __restrict__ cnt,
                                               int* __restrict__ off,
                                               int* __restrict__ bsum) {
    __shared__ int s[256];
    int t = threadIdx.x, i = blockIdx.x*256 + t;
    int v = (i < NTOT) ? cnt[i] : 0;
    s[t] = v; __syncthreads();
    #pragma unroll
    for (int o = 1; o < 256; o <<= 1) {
        int a = (t >= o) ? s[t-o] : 0; __syncthreads();
        s[t] += a; __syncthreads();
    }
    if (i < NTOT) off[i] = s[t] - v;
    if (t == 255) bsum[blockIdx.x] = s[255];
}

__global__ __launch_bounds__(1024) void k_scan2(int* bsum) {   // 782 totals
    __shared__ int s[1024];
    int t = threadIdx.x;
    int v = (t < 782) ? bsum[t] : 0;
    s[t] = v; __syncthreads();
    for (int o = 1; o < 1024; o <<= 1) {
        int a = (t >= o) ? s[t-o] : 0; __syncthreads();
        s[t] += a; __syncthreads();
    }
    if (t < 782) bsum[t] = s[t] - v;
}

__global__ __launch_bounds__(256) void k_scan3(int* __restrict__ off,
                                               const int* __restrict__ bsum,
                                               int* __restrict__ cur) {
    int i = blockIdx.x*256 + threadIdx.x;
    if (i < NTOT) { int o = off[i] + bsum[blockIdx.x]; off[i] = o; cur[i] = o; }
    if (i == 0) off[NTOT] = EE;
}

__global__ __launch_bounds__(256) void k_fill(const int* __restrict__ dst,
                                              int* __restrict__ cur,
                                              int* __restrict__ eidx) {
    int e = blockIdx.x*256 + threadIdx.x;
    if (e < EE) { int p = atomicAdd(&cur[dst[e]], 1); eidx[p] = e; }
}

// deg via CSR (no float atomics): deg = 1 + sum(ew); dinv = rsqrt
__global__ __launch_bounds__(256) void k_deg(const int* __restrict__ off,
                                             const int* __restrict__ eidx,
                                             const float* __restrict__ ew,
                                             float* __restrict__ dinv) {
    int n = blockIdx.x*256 + threadIdx.x;
    if (n >= NTOT) return;
    int e0 = off[n], e1 = off[n+1];
    float dg = 1.f;
    for (int e = e0; e < e1; ++e) dg += ew[eidx[e]];
    dinv[n] = rsqrtf(dg);
}

// layer-1 scalar aggregation (T=1 rank-1 trick):
// sagg[n] = dinv[n]*sum_e dinv[src]*ew*x[src] + dinv[n]^2*x[n]
__global__ __launch_bounds__(256) void k_sagg(const int* __restrict__ off,
                                              const int* __restrict__ eidx,
                                              const int* __restrict__ src,
                                              const float* __restrict__ ew,
                                              const float* __restrict__ x,
                                              const float* __restrict__ dinv,
                                              float* __restrict__ sagg) {
    int n = blockIdx.x*256 + threadIdx.x;
    if (n >= NTOT) return;
    int e0 = off[n], e1 = off[n+1];
    float s = 0.f;
    for (int e = e0; e < e1; ++e) {
        int idx = eidx[e];
        int sr = src[idx];
        s += dinv[sr]*ew[idx]*x[sr];
    }
    float di = dinv[n];
    sagg[n] = di*s + di*di*x[n];
}

// pack wih/whh into MFMA B-frag-linear bf16: tile tau (0..23 ih, 24..47 hh)
// wpack[tau*64+lane] = 8 bf16 = W[lt*16+(lane&15)][ks*32+(lane>>4)*8 + 0..7]
__global__ __launch_bounds__(256) void k_wprep(const float* __restrict__ wih,
                                               const float* __restrict__ whh,
                                               uint4* __restrict__ wpack) {
    int v = blockIdx.x*256 + threadIdx.x;
    if (v >= 3072) return;
    int lane = v & 63, tau = v >> 6;
    const float* W = (tau < 24) ? wih : whh;
    int tt = tau % 24;
    int lt = tt >> 1, ks = tt & 1;
    const float* s = W + (lt*16 + (lane & 15))*64 + ks*32 + (lane >> 4)*8;
    uint4 o;
    o.x = f2bf(s[0]) | (f2bf(s[1]) << 16);
    o.y = f2bf(s[2]) | (f2bf(s[3]) << 16);
    o.z = f2bf(s[4]) | (f2bf(s[5]) << 16);
    o.w = f2bf(s[6]) | (f2bf(s[7]) << 16);
    wpack[v] = o;
}

// fused: y1 = relu(sagg*W1 + b1)  ->  A2 = y1 @ W2   (W2 f32 in LDS)
__global__ __launch_bounds__(256) void k_l12(const float* __restrict__ sagg,
                                             const float* __restrict__ W1,
                                             const float* __restrict__ b1,
                                             const float* __restrict__ W2,
                                             float* __restrict__ A2) {
    __shared__ float ysh[64][68];
    __shared__ float wsh[64*68];              // W2 row k at k*68, f32
    int t = threadIdx.x;
    int n0 = blockIdx.x * 64;
    #pragma unroll
    for (int i = 0; i < 16; ++i) {
        int v = t + i*256;                    // coalesced global read of W2
        wsh[(v >> 6)*68 + (v & 63)] = W2[v];
    }
    {
        int row = t >> 2, c0 = (t & 3) * 16;
        float sv = sagg[n0 + row];
        #pragma unroll
        for (int q = 0; q < 4; ++q) {
            float4 w  = *(const float4*)(W1 + c0 + q*4);
            float4 bb = *(const float4*)(b1 + c0 + q*4);
            ysh[row][c0+q*4+0] = fmaxf(sv*w.x + bb.x, 0.f);
            ysh[row][c0+q*4+1] = fmaxf(sv*w.y + bb.y, 0.f);
            ysh[row][c0+q*4+2] = fmaxf(sv*w.z + bb.z, 0.f);
            ysh[row][c0+q*4+3] = fmaxf(sv*w.w + bb.w, 0.f);
        }
    }
    __syncthreads();
    int p = t >> 3, c = t & 7;
    float acc0[8], acc1[8];
    #pragma unroll
    for (int j = 0; j < 8; ++j) { acc0[j] = 0.f; acc1[j] = 0.f; }
    #pragma unroll 4
    for (int k = 0; k < 64; ++k) {
        float y0 = ysh[p][k], y1 = ysh[p+32][k];
        const float* wr = wsh + k*68 + c*8;
        float4 w0 = *(const float4*)wr;
        float4 w1 = *(const float4*)(wr + 4);
        acc0[0] += y0*w0.x; acc0[1] += y0*w0.y; acc0[2] += y0*w0.z; acc0[3] += y0*w0.w;
        acc0[4] += y0*w1.x; acc0[5] += y0*w1.y; acc0[6] += y0*w1.z; acc0[7] += y0*w1.w;
        acc1[0] += y1*w0.x; acc1[1] += y1*w0.y; acc1[2] += y1*w0.z; acc1[3] += y1*w0.w;
        acc1[4] += y1*w1.x; acc1[5] += y1*w1.y; acc1[6] += y1*w1.z; acc1[7] += y1*w1.w;
    }
    int na = n0 + p, nb = n0 + p + 32, cb = c*8;
    float4 s0 = {acc0[0],acc0[1],acc0[2],acc0[3]};
    float4 s1 = {acc0[4],acc0[5],acc0[6],acc0[7]};
    float4 s2 = {acc1[0],acc1[1],acc1[2],acc1[3]};
    float4 s3 = {acc1[4],acc1[5],acc1[6],acc1[7]};
    *(float4*)(A2 + (size_t)na*64 + cb)     = s0;
    *(float4*)(A2 + (size_t)na*64 + cb + 4) = s1;
    *(float4*)(A2 + (size_t)nb*64 + cb)     = s2;
    *(float4*)(A2 + (size_t)nb*64 + cb + 4) = s3;
}

// CSR vector gather (layer 2): B2[d,:] = relu(sum norm*A2[src] + dinv^2*A2[d] + b2)
__global__ __launch_bounds__(256) void k_gather(const float* __restrict__ A,
                                                const int* __restrict__ eidx,
                                                const int* __restrict__ off,
                                                const int* __restrict__ src,
                                                const float* __restrict__ ew,
                                                const float* __restrict__ dinv,
                                                const float* __restrict__ bias,
                                                float* __restrict__ B) {
    int wv = (blockIdx.x*256 + threadIdx.x) >> 6;   // wave index = node
    int lane = threadIdx.x & 63;
    if (wv >= NTOT) return;
    int e0 = off[wv], e1 = off[wv+1];
    float di = dinv[wv];
    float acc = di*di * A[(size_t)wv*64 + lane];
    for (int e = e0; e < e1; ++e) {
        int idx = eidx[e];
        int s = src[idx];
        float nrm = dinv[s] * ew[idx] * di;
        acc += nrm * A[(size_t)s*64 + lane];
    }
    B[(size_t)wv*64 + lane] = fmaxf(acc + bias[lane], 0.f);
}

// ---------- MFMA GRU + FC head — minimal, no LDS fragment staging ----------
// 256 thr = 4 waves, 64 nodes/block; wave w owns nodes n0+w*16..+15.
// A-frag (y or h): lane l = row (l&15), 8 contiguous k at (l>>4)*8 (+32 for 2nd half).
// B-frag (weights): k_wprep layout, same contiguous-8 slot pattern (sigma-invariant).
// C: row(node)=(lane>>4)*4+reg, col(gate)=lane&15  [m89-verified convention].
// Split-bf16 activations (hi+lo) x bf16 weights: only weight rounding survives.
__global__ __launch_bounds__(256) void k_gru(const float* B2,
                                             const float* __restrict__ h_in,
                                             const uint4* __restrict__ wpack,
                                             const float* __restrict__ bih,
                                             const float* __restrict__ bhh,
                                             const float* __restrict__ fcw,
                                             const float* __restrict__ fcb,
                                             float* __restrict__ out,
                                             float* hnew) {
    int t = threadIdx.x;
    int lane = t & 63, w = t >> 6;
    int n0 = blockIdx.x * 64;
    int rowA = n0 + w*16 + (lane & 15);
    int kb = (lane >> 4) * 8;
    float yf[16], hb[16];
    {
        const float4* yp = (const float4*)(B2 + (size_t)rowA*64 + kb);
        const float4* hp = (const float4*)(h_in + (size_t)rowA*64 + kb);
        *(float4*)&yf[0]  = yp[0]; *(float4*)&yf[4]  = yp[1];
        *(float4*)&yf[8]  = yp[8]; *(float4*)&yf[12] = yp[9];   // +32 floats
        *(float4*)&hb[0]  = hp[0]; *(float4*)&hb[4]  = hp[1];
        *(float4*)&hb[8]  = hp[8]; *(float4*)&hb[12] = hp[9];
    }
    short8v ya0h = packhi8(&yf[0]), ya1h = packhi8(&yf[8]);
    short8v ya0l = packlo8(&yf[0]), ya1l = packlo8(&yf[8]);
    short8v ha0h = packhi8(&hb[0]), ha1h = packhi8(&hb[8]);
    short8v ha0l = packlo8(&hb[0]), ha1l = packlo8(&hb[8]);
    float po[4][5] = {};
    #pragma unroll
    for (int lt = 0; lt < 4; ++lt) {
        // weight tiles: r-gates = tile lt, z = lt+4, n = lt+8; hh at +1536
        short8v wbr0 = *(const short8v*)&wpack[(lt*2+0)*64 + lane];
        short8v wbr1 = *(const short8v*)&wpack[(lt*2+1)*64 + lane];
        short8v wbz0 = *(const short8v*)&wpack[((lt+4)*2+0)*64 + lane];
        short8v wbz1 = *(const short8v*)&wpack[((lt+4)*2+1)*64 + lane];
        short8v wbn0 = *(const short8v*)&wpack[((lt+8)*2+0)*64 + lane];
        short8v wbn1 = *(const short8v*)&wpack[((lt+8)*2+1)*64 + lane];
        short8v vbr0 = *(const short8v*)&wpack[1536 + (lt*2+0)*64 + lane];
        short8v vbr1 = *(const short8v*)&wpack[1536 + (lt*2+1)*64 + lane];
        short8v vbz0 = *(const short8v*)&wpack[1536 + ((lt+4)*2+0)*64 + lane];
        short8v vbz1 = *(const short8v*)&wpack[1536 + ((lt+4)*2+1)*64 + lane];
        short8v vbn0 = *(const short8v*)&wpack[1536 + ((lt+8)*2+0)*64 + lane];
        short8v vbn1 = *(const short8v*)&wpack[1536 + ((lt+8)*2+1)*64 + lane];
        f32x4 aR  = {0.f,0.f,0.f,0.f};   // gi_r + gh_r
        f32x4 aZ  = {0.f,0.f,0.f,0.f};   // gi_z + gh_z
        f32x4 aNi = {0.f,0.f,0.f,0.f};   // gi_n
        f32x4 aNh = {0.f,0.f,0.f,0.f};   // gh_n
        aR = __builtin_amdgcn_mfma_f32_16x16x32_bf16(ya0h, wbr0, aR, 0, 0, 0);
        aR = __builtin_amdgcn_mfma_f32_16x16x32_bf16(ya1h, wbr1, aR, 0, 0, 0);
        aR = __builtin_amdgcn_mfma_f32_16x16x32_bf16(ya0l, wbr0, aR, 0, 0, 0);
        aR = __builtin_amdgcn_mfma_f32_16x16x32_bf16(ya1l, wbr1, aR, 0, 0, 0);
        aR = __builtin_amdgcn_mfma_f32_16x16x32_bf16(ha0h, vbr0, aR, 0, 0, 0);
        aR = __builtin_amdgcn_mfma_f32_16x16x32_bf16(ha1h, vbr1, aR, 0, 0, 0);
        aR = __builtin_amdgcn_mfma_f32_16x16x32_bf16(ha0l, vbr0, aR, 0, 0, 0);
        aR = __builtin_amdgcn_mfma_f32_16x16x32_bf16(ha1l, vbr1, aR, 0, 0, 0);
        aZ = __builtin_amdgcn_mfma_f32_16x16x32_bf16(ya0h, wbz0, aZ, 0, 0, 0);
        aZ = __builtin_amdgcn_mfma_f32_16x16x32_bf16(ya1h, wbz1, aZ, 0, 0, 0);
        aZ = __builtin_amdgcn_mfma_f32_16x16x32_bf16(ya0l, wbz0, aZ, 0, 0, 0);
        aZ = __builtin_amdgcn_mfma_f32_16x16x32_bf16(ya1l, wbz1, aZ, 0, 0, 0);
        aZ = __builtin_amdgcn_mfma_f32_16x16x32_bf16(ha0h, vbz0, aZ, 0, 0, 0);
        aZ = __builtin_amdgcn_mfma_f32_16x16x32_bf16(ha1h, vbz1, aZ, 0, 0, 0);
        aZ = __builtin_amdgcn_mfma_f32_16x16x32_bf16(ha0l, vbz0, aZ, 0, 0, 0);
        aZ = __builtin_amdgcn_mfma_f32_16x16x32_bf16(ha1l, vbz1, aZ, 0, 0, 0);
        aNi = __builtin_amdgcn_mfma_f32_16x16x32_bf16(ya0h, wbn0, aNi, 0, 0, 0);
        aNi = __builtin_amdgcn_mfma_f32_16x16x32_bf16(ya1h, wbn1, aNi, 0, 0, 0);
        aNi = __builtin_amdgcn_mfma_f32_16x16x32_bf16(ya0l, wbn0, aNi, 0, 0, 0);
        aNi = __builtin_amdgcn_mfma_f32_16x16x32_bf16(ya1l, wbn1, aNi, 0, 0, 0);
        aNh = __builtin_amdgcn_mfma_f32_16x16x32_bf16(ha0h, vbn0, aNh, 0, 0, 0);
        aNh = __builtin_amdgcn_mfma_f32_16x16x32_bf16(ha1h, vbn1, aNh, 0, 0, 0);
        aNh = __builtin_amdgcn_mfma_f32_16x16x32_bf16(ha0l, vbn0, aNh, 0, 0, 0);
        aNh = __builtin_amdgcn_mfma_f32_16x16x32_bf16(ha1l, vbn1, aNh, 0, 0, 0);
        int l = lt*16 + (lane & 15);
        float br = bih[l] + bhh[l];
        float bz = bih[64+l] + bhh[64+l];
        float bn = bih[128+l];
        float cn = bhh[128+l];
        float fw0 = fcw[l*5+0], fw1 = fcw[l*5+1], fw2 = fcw[l*5+2],
              fw3 = fcw[l*5+3], fw4 = fcw[l*5+4];
        #pragma unroll
        for (int r4 = 0; r4 < 4; ++r4) {
            int row = n0 + w*16 + (lane >> 4)*4 + r4;
            float rg = sigm(aR[r4] + br);
            float zg = sigm(aZ[r4] + bz);
            float ng = tanh_f(aNi[r4] + bn + rg*(aNh[r4] + cn));
            float hfv = h_in[(size_t)row*64 + l];
            float hnv = (1.f - zg)*ng + zg*hfv;
            hnew[(size_t)row*64 + l] = hnv;
            po[r4][0] += hnv*fw0; po[r4][1] += hnv*fw1; po[r4][2] += hnv*fw2;
            po[r4][3] += hnv*fw3; po[r4][4] += hnv*fw4;
        }
    }
    // FC reduce across the 16 gate-lanes of each group
    #pragma unroll
    for (int r4 = 0; r4 < 4; ++r4)
        #pragma unroll
        for (int j = 0; j < 5; ++j) {
            float v = po[r4][j];
            v += __shfl_xor(v, 1); v += __shfl_xor(v, 2);
            v += __shfl_xor(v, 4); v += __shfl_xor(v, 8);
            po[r4][j] = v;
        }
    if ((lane & 15) == 0) {
        #pragma unroll
        for (int r4 = 0; r4 < 4; ++r4) {
            int node = n0 + w*16 + (lane >> 4)*4 + r4;
            #pragma unroll
            for (int j = 0; j < 5; ++j) out[(size_t)node*5 + j] = po[r4][j] + fcb[j];
        }
    }
}

extern "C" void kernel_launch(void* const* d_in, const int* in_sizes, int n_in,
                              void* d_out, int out_size, void* d_ws, size_t ws_size,
                              hipStream_t stream) {
    const float* x   = (const float*)d_in[0];
    const float* ew  = (const float*)d_in[1];
    const float* h   = (const float*)d_in[2];
    const float* W1  = (const float*)d_in[3];
    const float* b1  = (const float*)d_in[4];
    const float* W2  = (const float*)d_in[5];
    const float* b2  = (const float*)d_in[6];
    const float* wih = (const float*)d_in[7];
    const float* whh = (const float*)d_in[8];
    const float* bih = (const float*)d_in[9];
    const float* bhh = (const float*)d_in[10];
    const float* fcw = (const float*)d_in[11];
    const float* fcb = (const float*)d_in[12];
    const int*   ei  = (const int*)d_in[13];
    const int* src = ei;
    const int* dst = ei + EE;

    // ws: A2 @0 (51.2MB) | eidx @51.2MB (4.8MB) | wpack @56MB (48KB)
    float* A2    = (float*)d_ws;
    int*   eidx  = (int*)((char*)d_ws + 51200000);
    uint4* wpack = (uint4*)((char*)d_ws + 56000000);
    // d_out head (first NTOT*5 floats, dead until k_gru epilogue) hosts CSR + scalars
    int*   cnt  = (int*)d_out;                    // 200000, reused as fill cursor
    int*   off  = cnt + NTOT;                     // 200001
    int*   bsum = off + NTOT + 1;                 // 782
    float* dinv = (float*)d_out + 401024;
    float* sagg = (float*)d_out + 601024;
    float* out  = (float*)d_out;
    float* B2   = out + (size_t)NTOT*5;           // d_out tail: y2 buffer, finally hnew

    k_init  <<<782,   256, 0, stream>>>(cnt);
    k_cnt   <<<4688,  256, 0, stream>>>(dst, cnt);
    k_scan1 <<<782,   256, 0, stream>>>(cnt, off, bsum);
    k_scan2 <<<1,    1024, 0, stream>>>(bsum);
    k_scan3 <<<782,   256, 0, stream>>>(off, bsum, cnt);
    k_fill  <<<4688,  256, 0, stream>>>(dst, cnt, eidx);
    k_deg   <<<782,   256, 0, stream>>>(off, eidx, ew, dinv);
    k_sagg  <<<782,   256, 0, stream>>>(off, eidx, src, ew, x, dinv, sagg);
    k_wprep <<<12,    256, 0, stream>>>(wih, whh, wpack);
    k_l12   <<<3125,  256, 0, stream>>>(sagg, W1, b1, W2, A2);
    k_gather<<<50000, 256, 0, stream>>>(A2, eidx, off, src, ew, dinv, b2, B2);
    k_gru   <<<3125,  256, 0, stream>>>(B2, h, wpack, bih, bhh, fcw, fcb, out, B2);
}

// Round 10
// 366.813 us; speedup vs baseline: 9.2601x; 1.4031x over previous
//
#include <hip/hip_runtime.h>

#define NTOT 200000
#define EE   1200000

typedef unsigned int u32;
typedef __attribute__((ext_vector_type(8))) short short8v;
typedef __attribute__((ext_vector_type(4))) float f32x4;

__device__ __forceinline__ float rcpf(float x) { return __builtin_amdgcn_rcpf(x); }
__device__ __forceinline__ float sigm(float x) { return rcpf(1.f + __expf(-x)); }
__device__ __forceinline__ float tanh_f(float x) { return 1.f - 2.f * rcpf(__expf(2.f * x) + 1.f); }
__device__ __forceinline__ u32 f2bf(float f) {           // RNE f32->bf16
    u32 u = __float_as_uint(f);
    return (u + 0x7fffu + ((u >> 16) & 1u)) >> 16;
}
__device__ __forceinline__ float bf2f(u32 b) { return __uint_as_float(b << 16); }
__device__ __forceinline__ float bf_lo(u32 p) { return __uint_as_float(p << 16); }
__device__ __forceinline__ float bf_hi(u32 p) { return __uint_as_float(p & 0xffff0000u); }

__device__ __forceinline__ short8v packhi8(const float* v) {
    union { u32 u[4]; short8v s; } r;
    r.u[0] = f2bf(v[0]) | (f2bf(v[1]) << 16);
    r.u[1] = f2bf(v[2]) | (f2bf(v[3]) << 16);
    r.u[2] = f2bf(v[4]) | (f2bf(v[5]) << 16);
    r.u[3] = f2bf(v[6]) | (f2bf(v[7]) << 16);
    return r.s;
}
__device__ __forceinline__ short8v packlo8(const float* v) {
    float q[8];
    #pragma unroll
    for (int i = 0; i < 8; ++i) q[i] = v[i] - bf2f(f2bf(v[i]));
    union { u32 u[4]; short8v s; } r;
    r.u[0] = f2bf(q[0]) | (f2bf(q[1]) << 16);
    r.u[1] = f2bf(q[2]) | (f2bf(q[3]) << 16);
    r.u[2] = f2bf(q[4]) | (f2bf(q[5]) << 16);
    r.u[3] = f2bf(q[6]) | (f2bf(q[7]) << 16);
    return r.s;
}

// ---------- degree + CSR build ----------
__global__ __launch_bounds__(256) void k_init(float* deg, int* cnt) {
    int n = blockIdx.x*256 + threadIdx.x;
    if (n < NTOT) { deg[n] = 1.0f; cnt[n] = 0; }
}

__global__ __launch_bounds__(256) void k_degcnt(const float* __restrict__ ew,
                                                const int* __restrict__ dst,
                                                float* __restrict__ deg,
                                                int* __restrict__ cnt) {
    int e = blockIdx.x*256 + threadIdx.x;
    if (e < EE) {
        int d = dst[e];
        atomicAdd(&deg[d], ew[e]);
        atomicAdd(&cnt[d], 1);
    }
}

__global__ __launch_bounds__(256) void k_dinv(float* deg) {
    int n = blockIdx.x*256 + threadIdx.x;
    if (n < NTOT) deg[n] = rsqrtf(deg[n]);
}

__global__ __launch_bounds__(256) void k_scan1(const int* __restrict__ cnt,
                                               int* __restrict__ off,
                                               int* __restrict__ bsum) {
    __shared__ int s[256];
    int t = threadIdx.x, i = blockIdx.x*256 + t;
    int v = (i < NTOT) ? cnt[i] : 0;
    s[t] = v; __syncthreads();
    #pragma unroll
    for (int o = 1; o < 256; o <<= 1) {
        int a = (t >= o) ? s[t-o] : 0; __syncthreads();
        s[t] += a; __syncthreads();
    }
    if (i < NTOT) off[i] = s[t] - v;
    if (t == 255) bsum[blockIdx.x] = s[255];
}

__global__ __launch_bounds__(1024) void k_scan2(int* bsum) {   // 782 totals
    __shared__ int s[1024];
    int t = threadIdx.x;
    int v = (t < 782) ? bsum[t] : 0;
    s[t] = v; __syncthreads();
    for (int o = 1; o < 1024; o <<= 1) {
        int a = (t >= o) ? s[t-o] : 0; __syncthreads();
        s[t] += a; __syncthreads();
    }
    if (t < 782) bsum[t] = s[t] - v;
}

__global__ __launch_bounds__(256) void k_scan3(int* __restrict__ off,
                                               const int* __restrict__ bsum,
                                               int* __restrict__ cur) {
    int i = blockIdx.x*256 + threadIdx.x;
    if (i < NTOT) { int o = off[i] + bsum[blockIdx.x]; off[i] = o; cur[i] = o; }
    if (i == 0) off[NTOT] = EE;
}

// fill CSR slots with precomputed {src, norm} — kills the eidx indirection downstream
__global__ __launch_bounds__(256) void k_fill(const int* __restrict__ src,
                                              const int* __restrict__ dst,
                                              const float* __restrict__ ew,
                                              const float* __restrict__ dinv,
                                              int* __restrict__ cur,
                                              uint2* __restrict__ epack) {
    int e = blockIdx.x*256 + threadIdx.x;
    if (e >= EE) return;
    int d = dst[e], s = src[e];
    float norm = dinv[s] * ew[e] * dinv[d];
    int p = atomicAdd(&cur[d], 1);
    epack[p] = make_uint2((u32)s, __float_as_uint(norm));
}

// layer-1 scalar aggregation (T=1 rank-1 trick):
// sagg[n] = sum_e norm*x[src] + dinv^2*x[n]    (norm already includes dinv[n])
__global__ __launch_bounds__(256) void k_sagg(const int* __restrict__ off,
                                              const uint2* __restrict__ epack,
                                              const float* __restrict__ x,
                                              const float* __restrict__ dinv,
                                              float* __restrict__ sagg) {
    int n = blockIdx.x*256 + threadIdx.x;
    if (n >= NTOT) return;
    int e0 = off[n], e1 = off[n+1];
    float s = 0.f;
    for (int e = e0; e < e1; ++e) {
        uint2 ep = epack[e];
        s += __uint_as_float(ep.y) * x[ep.x];
    }
    float di = dinv[n];
    sagg[n] = s + di*di*x[n];
}

// pack wih/whh into MFMA B-frag-linear bf16: tile tau (0..23 ih, 24..47 hh)
__global__ __launch_bounds__(256) void k_wprep(const float* __restrict__ wih,
                                               const float* __restrict__ whh,
                                               uint4* __restrict__ wpack) {
    int v = blockIdx.x*256 + threadIdx.x;
    if (v >= 3072) return;
    int lane = v & 63, tau = v >> 6;
    const float* W = (tau < 24) ? wih : whh;
    int tt = tau % 24;
    int lt = tt >> 1, ks = tt & 1;
    const float* s = W + (lt*16 + (lane & 15))*64 + ks*32 + (lane >> 4)*8;
    uint4 o;
    o.x = f2bf(s[0]) | (f2bf(s[1]) << 16);
    o.y = f2bf(s[2]) | (f2bf(s[3]) << 16);
    o.z = f2bf(s[4]) | (f2bf(s[5]) << 16);
    o.w = f2bf(s[6]) | (f2bf(s[7]) << 16);
    wpack[v] = o;
}

// fused: y1 = relu(sagg*W1 + b1)  ->  A2 = y1 @ W2, stored packed bf16 (128B/row)
__global__ __launch_bounds__(256) void k_l12(const float* __restrict__ sagg,
                                             const float* __restrict__ W1,
                                             const float* __restrict__ b1,
                                             const float* __restrict__ W2,
                                             u32* __restrict__ A2p) {
    __shared__ float ysh[64][68];
    __shared__ float wsh[64*68];              // W2 row k at k*68, f32
    int t = threadIdx.x;
    int n0 = blockIdx.x * 64;
    #pragma unroll
    for (int i = 0; i < 16; ++i) {
        int v = t + i*256;                    // coalesced global read of W2
        wsh[(v >> 6)*68 + (v & 63)] = W2[v];
    }
    {
        int row = t >> 2, c0 = (t & 3) * 16;
        float sv = sagg[n0 + row];
        #pragma unroll
        for (int q = 0; q < 4; ++q) {
            float4 w  = *(const float4*)(W1 + c0 + q*4);
            float4 bb = *(const float4*)(b1 + c0 + q*4);
            ysh[row][c0+q*4+0] = fmaxf(sv*w.x + bb.x, 0.f);
            ysh[row][c0+q*4+1] = fmaxf(sv*w.y + bb.y, 0.f);
            ysh[row][c0+q*4+2] = fmaxf(sv*w.z + bb.z, 0.f);
            ysh[row][c0+q*4+3] = fmaxf(sv*w.w + bb.w, 0.f);
        }
    }
    __syncthreads();
    int p = t >> 3, c = t & 7;
    float acc0[8], acc1[8];
    #pragma unroll
    for (int j = 0; j < 8; ++j) { acc0[j] = 0.f; acc1[j] = 0.f; }
    #pragma unroll 4
    for (int k = 0; k < 64; ++k) {
        float y0 = ysh[p][k], y1 = ysh[p+32][k];
        const float* wr = wsh + k*68 + c*8;
        float4 w0 = *(const float4*)wr;
        float4 w1 = *(const float4*)(wr + 4);
        acc0[0] += y0*w0.x; acc0[1] += y0*w0.y; acc0[2] += y0*w0.z; acc0[3] += y0*w0.w;
        acc0[4] += y0*w1.x; acc0[5] += y0*w1.y; acc0[6] += y0*w1.z; acc0[7] += y0*w1.w;
        acc1[0] += y1*w0.x; acc1[1] += y1*w0.y; acc1[2] += y1*w0.z; acc1[3] += y1*w0.w;
        acc1[4] += y1*w1.x; acc1[5] += y1*w1.y; acc1[6] += y1*w1.z; acc1[7] += y1*w1.w;
    }
    int na = n0 + p, nb = n0 + p + 32;
    uint4 pk;
    pk.x = f2bf(acc0[0]) | (f2bf(acc0[1]) << 16);
    pk.y = f2bf(acc0[2]) | (f2bf(acc0[3]) << 16);
    pk.z = f2bf(acc0[4]) | (f2bf(acc0[5]) << 16);
    pk.w = f2bf(acc0[6]) | (f2bf(acc0[7]) << 16);
    *(uint4*)(A2p + (size_t)na*32 + c*4) = pk;
    pk.x = f2bf(acc1[0]) | (f2bf(acc1[1]) << 16);
    pk.y = f2bf(acc1[2]) | (f2bf(acc1[3]) << 16);
    pk.z = f2bf(acc1[4]) | (f2bf(acc1[5]) << 16);
    pk.w = f2bf(acc1[6]) | (f2bf(acc1[7]) << 16);
    *(uint4*)(A2p + (size_t)nb*32 + c*4) = pk;
}

// CSR gather, 4-edge ILP, bf16 rows:
// wave per node; group g (16 lanes) handles edges e0+g, e0+g+4, ...; lane q covers cols 4q..4q+3.
__global__ __launch_bounds__(256) void k_gather(const u32* __restrict__ A2p,
                                                const uint2* __restrict__ epack,
                                                const int* __restrict__ off,
                                                const float* __restrict__ dinv,
                                                const float* __restrict__ b2,
                                                float* __restrict__ B2) {
    int wv = (blockIdx.x*256 + threadIdx.x) >> 6;
    int lane = threadIdx.x & 63;
    if (wv >= NTOT) return;
    int g = lane >> 4, q = lane & 15;
    int e0 = off[wv], e1 = off[wv+1];
    float ax = 0.f, ay = 0.f, az = 0.f, aw = 0.f;
    for (int e = e0 + g; e < e1; e += 4) {
        uint2 ep = epack[e];
        int sr = (int)ep.x;
        float nrm = __uint_as_float(ep.y);
        uint2 pw = *(const uint2*)(A2p + (size_t)sr*32 + q*2);
        ax += nrm*bf_lo(pw.x); ay += nrm*bf_hi(pw.x);
        az += nrm*bf_lo(pw.y); aw += nrm*bf_hi(pw.y);
    }
    // reduce across the 4 edge-groups
    ax += __shfl_xor(ax, 16); ax += __shfl_xor(ax, 32);
    ay += __shfl_xor(ay, 16); ay += __shfl_xor(ay, 32);
    az += __shfl_xor(az, 16); az += __shfl_xor(az, 32);
    aw += __shfl_xor(aw, 16); aw += __shfl_xor(aw, 32);
    if (g == 0) {
        float di = dinv[wv], d2 = di*di;
        uint2 pw = *(const uint2*)(A2p + (size_t)wv*32 + q*2);
        float4 bb = *(const float4*)(b2 + q*4);
        float4 o;
        o.x = fmaxf(ax + d2*bf_lo(pw.x) + bb.x, 0.f);
        o.y = fmaxf(ay + d2*bf_hi(pw.x) + bb.y, 0.f);
        o.z = fmaxf(az + d2*bf_lo(pw.y) + bb.z, 0.f);
        o.w = fmaxf(aw + d2*bf_hi(pw.y) + bb.w, 0.f);
        *(float4*)(B2 + (size_t)wv*64 + q*4) = o;
    }
}

// ---------- MFMA GRU + FC head (round-8 proven) ----------
__global__ __launch_bounds__(256) void k_gru(const float* B2,
                                             const float* __restrict__ h_in,
                                             const uint4* __restrict__ wpack,
                                             const float* __restrict__ bih,
                                             const float* __restrict__ bhh,
                                             const float* __restrict__ fcw,
                                             const float* __restrict__ fcb,
                                             float* __restrict__ out,
                                             float* hnew) {
    int t = threadIdx.x;
    int lane = t & 63, w = t >> 6;
    int n0 = blockIdx.x * 64;
    int rowA = n0 + w*16 + (lane & 15);
    int kb = (lane >> 4) * 8;
    float yf[16], hb[16];
    {
        const float4* yp = (const float4*)(B2 + (size_t)rowA*64 + kb);
        const float4* hp = (const float4*)(h_in + (size_t)rowA*64 + kb);
        *(float4*)&yf[0]  = yp[0]; *(float4*)&yf[4]  = yp[1];
        *(float4*)&yf[8]  = yp[8]; *(float4*)&yf[12] = yp[9];   // +32 floats
        *(float4*)&hb[0]  = hp[0]; *(float4*)&hb[4]  = hp[1];
        *(float4*)&hb[8]  = hp[8]; *(float4*)&hb[12] = hp[9];
    }
    short8v ya0h = packhi8(&yf[0]), ya1h = packhi8(&yf[8]);
    short8v ya0l = packlo8(&yf[0]), ya1l = packlo8(&yf[8]);
    short8v ha0h = packhi8(&hb[0]), ha1h = packhi8(&hb[8]);
    short8v ha0l = packlo8(&hb[0]), ha1l = packlo8(&hb[8]);
    float po[4][5] = {};
    #pragma unroll
    for (int lt = 0; lt < 4; ++lt) {
        short8v wbr0 = *(const short8v*)&wpack[(lt*2+0)*64 + lane];
        short8v wbr1 = *(const short8v*)&wpack[(lt*2+1)*64 + lane];
        short8v wbz0 = *(const short8v*)&wpack[((lt+4)*2+0)*64 + lane];
        short8v wbz1 = *(const short8v*)&wpack[((lt+4)*2+1)*64 + lane];
        short8v wbn0 = *(const short8v*)&wpack[((lt+8)*2+0)*64 + lane];
        short8v wbn1 = *(const short8v*)&wpack[((lt+8)*2+1)*64 + lane];
        short8v vbr0 = *(const short8v*)&wpack[1536 + (lt*2+0)*64 + lane];
        short8v vbr1 = *(const short8v*)&wpack[1536 + (lt*2+1)*64 + lane];
        short8v vbz0 = *(const short8v*)&wpack[1536 + ((lt+4)*2+0)*64 + lane];
        short8v vbz1 = *(const short8v*)&wpack[1536 + ((lt+4)*2+1)*64 + lane];
        short8v vbn0 = *(const short8v*)&wpack[1536 + ((lt+8)*2+0)*64 + lane];
        short8v vbn1 = *(const short8v*)&wpack[1536 + ((lt+8)*2+1)*64 + lane];
        f32x4 aR  = {0.f,0.f,0.f,0.f};
        f32x4 aZ  = {0.f,0.f,0.f,0.f};
        f32x4 aNi = {0.f,0.f,0.f,0.f};
        f32x4 aNh = {0.f,0.f,0.f,0.f};
        aR = __builtin_amdgcn_mfma_f32_16x16x32_bf16(ya0h, wbr0, aR, 0, 0, 0);
        aR = __builtin_amdgcn_mfma_f32_16x16x32_bf16(ya1h, wbr1, aR, 0, 0, 0);
        aR = __builtin_amdgcn_mfma_f32_16x16x32_bf16(ya0l, wbr0, aR, 0, 0, 0);
        aR = __builtin_amdgcn_mfma_f32_16x16x32_bf16(ya1l, wbr1, aR, 0, 0, 0);
        aR = __builtin_amdgcn_mfma_f32_16x16x32_bf16(ha0h, vbr0, aR, 0, 0, 0);
        aR = __builtin_amdgcn_mfma_f32_16x16x32_bf16(ha1h, vbr1, aR, 0, 0, 0);
        aR = __builtin_amdgcn_mfma_f32_16x16x32_bf16(ha0l, vbr0, aR, 0, 0, 0);
        aR = __builtin_amdgcn_mfma_f32_16x16x32_bf16(ha1l, vbr1, aR, 0, 0, 0);
        aZ = __builtin_amdgcn_mfma_f32_16x16x32_bf16(ya0h, wbz0, aZ, 0, 0, 0);
        aZ = __builtin_amdgcn_mfma_f32_16x16x32_bf16(ya1h, wbz1, aZ, 0, 0, 0);
        aZ = __builtin_amdgcn_mfma_f32_16x16x32_bf16(ya0l, wbz0, aZ, 0, 0, 0);
        aZ = __builtin_amdgcn_mfma_f32_16x16x32_bf16(ya1l, wbz1, aZ, 0, 0, 0);
        aZ = __builtin_amdgcn_mfma_f32_16x16x32_bf16(ha0h, vbz0, aZ, 0, 0, 0);
        aZ = __builtin_amdgcn_mfma_f32_16x16x32_bf16(ha1h, vbz1, aZ, 0, 0, 0);
        aZ = __builtin_amdgcn_mfma_f32_16x16x32_bf16(ha0l, vbz0, aZ, 0, 0, 0);
        aZ = __builtin_amdgcn_mfma_f32_16x16x32_bf16(ha1l, vbz1, aZ, 0, 0, 0);
        aNi = __builtin_amdgcn_mfma_f32_16x16x32_bf16(ya0h, wbn0, aNi, 0, 0, 0);
        aNi = __builtin_amdgcn_mfma_f32_16x16x32_bf16(ya1h, wbn1, aNi, 0, 0, 0);
        aNi = __builtin_amdgcn_mfma_f32_16x16x32_bf16(ya0l, wbn0, aNi, 0, 0, 0);
        aNi = __builtin_amdgcn_mfma_f32_16x16x32_bf16(ya1l, wbn1, aNi, 0, 0, 0);
        aNh = __builtin_amdgcn_mfma_f32_16x16x32_bf16(ha0h, vbn0, aNh, 0, 0, 0);
        aNh = __builtin_amdgcn_mfma_f32_16x16x32_bf16(ha1h, vbn1, aNh, 0, 0, 0);
        aNh = __builtin_amdgcn_mfma_f32_16x16x32_bf16(ha0l, vbn0, aNh, 0, 0, 0);
        aNh = __builtin_amdgcn_mfma_f32_16x16x32_bf16(ha1l, vbn1, aNh, 0, 0, 0);
        int l = lt*16 + (lane & 15);
        float br = bih[l] + bhh[l];
        float bz = bih[64+l] + bhh[64+l];
        float bn = bih[128+l];
        float cn = bhh[128+l];
        float fw0 = fcw[l*5+0], fw1 = fcw[l*5+1], fw2 = fcw[l*5+2],
              fw3 = fcw[l*5+3], fw4 = fcw[l*5+4];
        #pragma unroll
        for (int r4 = 0; r4 < 4; ++r4) {
            int row = n0 + w*16 + (lane >> 4)*4 + r4;
            float rg = sigm(aR[r4] + br);
            float zg = sigm(aZ[r4] + bz);
            float ng = tanh_f(aNi[r4] + bn + rg*(aNh[r4] + cn));
            float hfv = h_in[(size_t)row*64 + l];
            float hnv = (1.f - zg)*ng + zg*hfv;
            hnew[(size_t)row*64 + l] = hnv;
            po[r4][0] += hnv*fw0; po[r4][1] += hnv*fw1; po[r4][2] += hnv*fw2;
            po[r4][3] += hnv*fw3; po[r4][4] += hnv*fw4;
        }
    }
    #pragma unroll
    for (int r4 = 0; r4 < 4; ++r4)
        #pragma unroll
        for (int j = 0; j < 5; ++j) {
            float v = po[r4][j];
            v += __shfl_xor(v, 1); v += __shfl_xor(v, 2);
            v += __shfl_xor(v, 4); v += __shfl_xor(v, 8);
            po[r4][j] = v;
        }
    if ((lane & 15) == 0) {
        #pragma unroll
        for (int r4 = 0; r4 < 4; ++r4) {
            int node = n0 + w*16 + (lane >> 4)*4 + r4;
            #pragma unroll
            for (int j = 0; j < 5; ++j) out[(size_t)node*5 + j] = po[r4][j] + fcb[j];
        }
    }
}

extern "C" void kernel_launch(void* const* d_in, const int* in_sizes, int n_in,
                              void* d_out, int out_size, void* d_ws, size_t ws_size,
                              hipStream_t stream) {
    const float* x   = (const float*)d_in[0];
    const float* ew  = (const float*)d_in[1];
    const float* h   = (const float*)d_in[2];
    const float* W1  = (const float*)d_in[3];
    const float* b1  = (const float*)d_in[4];
    const float* W2  = (const float*)d_in[5];
    const float* b2  = (const float*)d_in[6];
    const float* wih = (const float*)d_in[7];
    const float* whh = (const float*)d_in[8];
    const float* bih = (const float*)d_in[9];
    const float* bhh = (const float*)d_in[10];
    const float* fcw = (const float*)d_in[11];
    const float* fcb = (const float*)d_in[12];
    const int*   ei  = (const int*)d_in[13];
    const int* src = ei;
    const int* dst = ei + EE;

    // ws: A2p bf16 @0 (25.6MB) | epack @25.6MB (9.6MB) | wpack @35.2MB (48KB)
    u32*   A2p   = (u32*)d_ws;
    uint2* epack = (uint2*)((char*)d_ws + 25600000);
    uint4* wpack = (uint4*)((char*)d_ws + 35200000);
    // d_out head (first NTOT*5 floats, dead until k_gru epilogue) hosts CSR + scalars
    int*   cnt  = (int*)d_out;                    // 200000, reused as fill cursor
    int*   off  = cnt + NTOT;                     // 200001
    int*   bsum = off + NTOT + 1;                 // 782
    float* dinv = (float*)d_out + 401024;
    float* sagg = (float*)d_out + 601024;
    float* out  = (float*)d_out;
    float* B2   = out + (size_t)NTOT*5;           // d_out tail: y2 buffer, finally hnew

    k_init  <<<782,   256, 0, stream>>>(dinv, cnt);
    k_degcnt<<<4688,  256, 0, stream>>>(ew, dst, dinv, cnt);
    k_dinv  <<<782,   256, 0, stream>>>(dinv);
    k_scan1 <<<782,   256, 0, stream>>>(cnt, off, bsum);
    k_scan2 <<<1,    1024, 0, stream>>>(bsum);
    k_scan3 <<<782,   256, 0, stream>>>(off, bsum, cnt);
    k_fill  <<<4688,  256, 0, stream>>>(src, dst, ew, dinv, cnt, epack);
    k_sagg  <<<782,   256, 0, stream>>>(off, epack, x, dinv, sagg);
    k_wprep <<<12,    256, 0, stream>>>(wih, whh, wpack);
    k_l12   <<<3125,  256, 0, stream>>>(sagg, W1, b1, W2, A2p);
    k_gather<<<50000, 256, 0, stream>>>(A2p, epack, off, dinv, b2, B2);
    k_gru   <<<3125,  256, 0, stream>>>(B2, h, wpack, bih, bhh, fcw, fcb, out, B2);
}

// Round 11
// 311.627 us; speedup vs baseline: 10.8999x; 1.1771x over previous
//
#include <hip/hip_runtime.h>

#define NTOT 200000
#define EE   1200000

typedef unsigned int u32;
typedef unsigned long long u64;
typedef __attribute__((ext_vector_type(8))) short short8v;
typedef __attribute__((ext_vector_type(4))) float f32x4;

__device__ __forceinline__ float rcpf(float x) { return __builtin_amdgcn_rcpf(x); }
__device__ __forceinline__ float sigm(float x) { return rcpf(1.f + __expf(-x)); }
__device__ __forceinline__ float tanh_f(float x) { return 1.f - 2.f * rcpf(__expf(2.f * x) + 1.f); }
__device__ __forceinline__ u32 f2bf(float f) {           // RNE f32->bf16
    u32 u = __float_as_uint(f);
    return (u + 0x7fffu + ((u >> 16) & 1u)) >> 16;
}
__device__ __forceinline__ float bf2f(u32 b) { return __uint_as_float(b << 16); }
__device__ __forceinline__ float bf_lo(u32 p) { return __uint_as_float(p << 16); }
__device__ __forceinline__ float bf_hi(u32 p) { return __uint_as_float(p & 0xffff0000u); }

__device__ __forceinline__ short8v packhi8(const float* v) {
    union { u32 u[4]; short8v s; } r;
    r.u[0] = f2bf(v[0]) | (f2bf(v[1]) << 16);
    r.u[1] = f2bf(v[2]) | (f2bf(v[3]) << 16);
    r.u[2] = f2bf(v[4]) | (f2bf(v[5]) << 16);
    r.u[3] = f2bf(v[6]) | (f2bf(v[7]) << 16);
    return r.s;
}
__device__ __forceinline__ short8v packlo8(const float* v) {
    float q[8];
    #pragma unroll
    for (int i = 0; i < 8; ++i) q[i] = v[i] - bf2f(f2bf(v[i]));
    union { u32 u[4]; short8v s; } r;
    r.u[0] = f2bf(q[0]) | (f2bf(q[1]) << 16);
    r.u[1] = f2bf(q[2]) | (f2bf(q[3]) << 16);
    r.u[2] = f2bf(q[4]) | (f2bf(q[5]) << 16);
    r.u[3] = f2bf(q[6]) | (f2bf(q[7]) << 16);
    return r.s;
}

// ---------- degree+count in ONE u64 atomic: count @bit40, sum(ew) fixed-point 2^-24 ----------
__global__ __launch_bounds__(256) void k_degcnt(const float* __restrict__ ew,
                                                const int* __restrict__ dst,
                                                u64* __restrict__ pk) {
    int e = blockIdx.x*256 + threadIdx.x;
    if (e < EE) {
        u64 v = (1ull << 40) | (u64)(u32)__float2uint_rn(ew[e] * 16777216.f);
        atomicAdd(&pk[dst[e]], v);
    }
}

// scan of counts (from pk) + dinv = rsqrt(1 + fixsum*2^-24) fused
__global__ __launch_bounds__(256) void k_scan1(const u64* __restrict__ pk,
                                               int* __restrict__ off,
                                               int* __restrict__ bsum,
                                               float* __restrict__ dinv) {
    __shared__ int s[256];
    int t = threadIdx.x, i = blockIdx.x*256 + t;
    int v = 0;
    if (i < NTOT) {
        u64 p = pk[i];
        v = (int)(p >> 40);
        dinv[i] = rsqrtf(1.0f + (float)(p & 0xFFFFFFFFFFull) * 5.9604644775390625e-8f);
    }
    s[t] = v; __syncthreads();
    #pragma unroll
    for (int o = 1; o < 256; o <<= 1) {
        int a = (t >= o) ? s[t-o] : 0; __syncthreads();
        s[t] += a; __syncthreads();
    }
    if (i < NTOT) off[i] = s[t] - v;
    if (t == 255) bsum[blockIdx.x] = s[255];
}

__global__ __launch_bounds__(1024) void k_scan2(int* bsum) {   // 782 totals
    __shared__ int s[1024];
    int t = threadIdx.x;
    int v = (t < 782) ? bsum[t] : 0;
    s[t] = v; __syncthreads();
    for (int o = 1; o < 1024; o <<= 1) {
        int a = (t >= o) ? s[t-o] : 0; __syncthreads();
        s[t] += a; __syncthreads();
    }
    if (t < 782) bsum[t] = s[t] - v;
}

__global__ __launch_bounds__(256) void k_scan3(int* __restrict__ off,
                                               const int* __restrict__ bsum,
                                               int* __restrict__ cur) {
    int i = blockIdx.x*256 + threadIdx.x;
    if (i < NTOT) { int o = off[i] + bsum[blockIdx.x]; off[i] = o; cur[i] = o; }
    if (i == 0) off[NTOT] = EE;
}

// fill CSR slots with precomputed {src, norm}
__global__ __launch_bounds__(256) void k_fill(const int* __restrict__ src,
                                              const int* __restrict__ dst,
                                              const float* __restrict__ ew,
                                              const float* __restrict__ dinv,
                                              int* __restrict__ cur,
                                              uint2* __restrict__ epack) {
    int e = blockIdx.x*256 + threadIdx.x;
    if (e >= EE) return;
    int d = dst[e], s = src[e];
    float norm = dinv[s] * ew[e] * dinv[d];
    int p = atomicAdd(&cur[d], 1);
    epack[p] = make_uint2((u32)s, __float_as_uint(norm));
}

// layer-1 scalar aggregation (T=1 rank-1 trick)
__global__ __launch_bounds__(256) void k_sagg(const int* __restrict__ off,
                                              const uint2* __restrict__ epack,
                                              const float* __restrict__ x,
                                              const float* __restrict__ dinv,
                                              float* __restrict__ sagg) {
    int n = blockIdx.x*256 + threadIdx.x;
    if (n >= NTOT) return;
    int e0 = off[n], e1 = off[n+1];
    float s = 0.f;
    for (int e = e0; e < e1; ++e) {
        uint2 ep = epack[e];
        s += __uint_as_float(ep.y) * x[ep.x];
    }
    float di = dinv[n];
    sagg[n] = s + di*di*x[n];
}

// pack wih/whh into MFMA B-frag-linear bf16: tile tau (0..23 ih, 24..47 hh)
__global__ __launch_bounds__(256) void k_wprep(const float* __restrict__ wih,
                                               const float* __restrict__ whh,
                                               uint4* __restrict__ wpack) {
    int v = blockIdx.x*256 + threadIdx.x;
    if (v >= 3072) return;
    int lane = v & 63, tau = v >> 6;
    const float* W = (tau < 24) ? wih : whh;
    int tt = tau % 24;
    int lt = tt >> 1, ks = tt & 1;
    const float* s = W + (lt*16 + (lane & 15))*64 + ks*32 + (lane >> 4)*8;
    uint4 o;
    o.x = f2bf(s[0]) | (f2bf(s[1]) << 16);
    o.y = f2bf(s[2]) | (f2bf(s[3]) << 16);
    o.z = f2bf(s[4]) | (f2bf(s[5]) << 16);
    o.w = f2bf(s[6]) | (f2bf(s[7]) << 16);
    wpack[v] = o;
}

// fused: y1 = relu(sagg*W1 + b1)  ->  A2 = y1 @ W2, stored packed bf16 (128B/row)
__global__ __launch_bounds__(256) void k_l12(const float* __restrict__ sagg,
                                             const float* __restrict__ W1,
                                             const float* __restrict__ b1,
                                             const float* __restrict__ W2,
                                             u32* __restrict__ A2p) {
    __shared__ float ysh[64][68];
    __shared__ float wsh[64*68];              // W2 row k at k*68, f32
    int t = threadIdx.x;
    int n0 = blockIdx.x * 64;
    #pragma unroll
    for (int i = 0; i < 16; ++i) {
        int v = t + i*256;                    // coalesced global read of W2
        wsh[(v >> 6)*68 + (v & 63)] = W2[v];
    }
    {
        int row = t >> 2, c0 = (t & 3) * 16;
        float sv = sagg[n0 + row];
        #pragma unroll
        for (int q = 0; q < 4; ++q) {
            float4 w  = *(const float4*)(W1 + c0 + q*4);
            float4 bb = *(const float4*)(b1 + c0 + q*4);
            ysh[row][c0+q*4+0] = fmaxf(sv*w.x + bb.x, 0.f);
            ysh[row][c0+q*4+1] = fmaxf(sv*w.y + bb.y, 0.f);
            ysh[row][c0+q*4+2] = fmaxf(sv*w.z + bb.z, 0.f);
            ysh[row][c0+q*4+3] = fmaxf(sv*w.w + bb.w, 0.f);
        }
    }
    __syncthreads();
    int p = t >> 3, c = t & 7;
    float acc0[8], acc1[8];
    #pragma unroll
    for (int j = 0; j < 8; ++j) { acc0[j] = 0.f; acc1[j] = 0.f; }
    #pragma unroll 4
    for (int k = 0; k < 64; ++k) {
        float y0 = ysh[p][k], y1 = ysh[p+32][k];
        const float* wr = wsh + k*68 + c*8;
        float4 w0 = *(const float4*)wr;
        float4 w1 = *(const float4*)(wr + 4);
        acc0[0] += y0*w0.x; acc0[1] += y0*w0.y; acc0[2] += y0*w0.z; acc0[3] += y0*w0.w;
        acc0[4] += y0*w1.x; acc0[5] += y0*w1.y; acc0[6] += y0*w1.z; acc0[7] += y0*w1.w;
        acc1[0] += y1*w0.x; acc1[1] += y1*w0.y; acc1[2] += y1*w0.z; acc1[3] += y1*w0.w;
        acc1[4] += y1*w1.x; acc1[5] += y1*w1.y; acc1[6] += y1*w1.z; acc1[7] += y1*w1.w;
    }
    int na = n0 + p, nb = n0 + p + 32;
    uint4 pk;
    pk.x = f2bf(acc0[0]) | (f2bf(acc0[1]) << 16);
    pk.y = f2bf(acc0[2]) | (f2bf(acc0[3]) << 16);
    pk.z = f2bf(acc0[4]) | (f2bf(acc0[5]) << 16);
    pk.w = f2bf(acc0[6]) | (f2bf(acc0[7]) << 16);
    *(uint4*)(A2p + (size_t)na*32 + c*4) = pk;
    pk.x = f2bf(acc1[0]) | (f2bf(acc1[1]) << 16);
    pk.y = f2bf(acc1[2]) | (f2bf(acc1[3]) << 16);
    pk.z = f2bf(acc1[4]) | (f2bf(acc1[5]) << 16);
    pk.w = f2bf(acc1[6]) | (f2bf(acc1[7]) << 16);
    *(uint4*)(A2p + (size_t)nb*32 + c*4) = pk;
}

// CSR gather, 4-edge ILP, bf16 rows
__global__ __launch_bounds__(256) void k_gather(const u32* __restrict__ A2p,
                                                const uint2* __restrict__ epack,
                                                const int* __restrict__ off,
                                                const float* __restrict__ dinv,
                                                const float* __restrict__ b2,
                                                float* __restrict__ B2) {
    int wv = (blockIdx.x*256 + threadIdx.x) >> 6;
    int lane = threadIdx.x & 63;
    if (wv >= NTOT) return;
    int g = lane >> 4, q = lane & 15;
    int e0 = off[wv], e1 = off[wv+1];
    float ax = 0.f, ay = 0.f, az = 0.f, aw = 0.f;
    for (int e = e0 + g; e < e1; e += 4) {
        uint2 ep = epack[e];
        int sr = (int)ep.x;
        float nrm = __uint_as_float(ep.y);
        uint2 pw = *(const uint2*)(A2p + (size_t)sr*32 + q*2);
        ax += nrm*bf_lo(pw.x); ay += nrm*bf_hi(pw.x);
        az += nrm*bf_lo(pw.y); aw += nrm*bf_hi(pw.y);
    }
    ax += __shfl_xor(ax, 16); ax += __shfl_xor(ax, 32);
    ay += __shfl_xor(ay, 16); ay += __shfl_xor(ay, 32);
    az += __shfl_xor(az, 16); az += __shfl_xor(az, 32);
    aw += __shfl_xor(aw, 16); aw += __shfl_xor(aw, 32);
    if (g == 0) {
        float di = dinv[wv], d2 = di*di;
        uint2 pw = *(const uint2*)(A2p + (size_t)wv*32 + q*2);
        float4 bb = *(const float4*)(b2 + q*4);
        float4 o;
        o.x = fmaxf(ax + d2*bf_lo(pw.x) + bb.x, 0.f);
        o.y = fmaxf(ay + d2*bf_hi(pw.x) + bb.y, 0.f);
        o.z = fmaxf(az + d2*bf_lo(pw.y) + bb.z, 0.f);
        o.w = fmaxf(aw + d2*bf_hi(pw.y) + bb.w, 0.f);
        *(float4*)(B2 + (size_t)wv*64 + q*4) = o;
    }
}

// ---------- MFMA GRU + FC head (round-8 proven) ----------
__global__ __launch_bounds__(256) void k_gru(const float* B2,
                                             const float* __restrict__ h_in,
                                             const uint4* __restrict__ wpack,
                                             const float* __restrict__ bih,
                                             const float* __restrict__ bhh,
                                             const float* __restrict__ fcw,
                                             const float* __restrict__ fcb,
                                             float* __restrict__ out,
                                             float* hnew) {
    int t = threadIdx.x;
    int lane = t & 63, w = t >> 6;
    int n0 = blockIdx.x * 64;
    int rowA = n0 + w*16 + (lane & 15);
    int kb = (lane >> 4) * 8;
    float yf[16], hb[16];
    {
        const float4* yp = (const float4*)(B2 + (size_t)rowA*64 + kb);
        const float4* hp = (const float4*)(h_in + (size_t)rowA*64 + kb);
        *(float4*)&yf[0]  = yp[0]; *(float4*)&yf[4]  = yp[1];
        *(float4*)&yf[8]  = yp[8]; *(float4*)&yf[12] = yp[9];   // +32 floats
        *(float4*)&hb[0]  = hp[0]; *(float4*)&hb[4]  = hp[1];
        *(float4*)&hb[8]  = hp[8]; *(float4*)&hb[12] = hp[9];
    }
    short8v ya0h = packhi8(&yf[0]), ya1h = packhi8(&yf[8]);
    short8v ya0l = packlo8(&yf[0]), ya1l = packlo8(&yf[8]);
    short8v ha0h = packhi8(&hb[0]), ha1h = packhi8(&hb[8]);
    short8v ha0l = packlo8(&hb[0]), ha1l = packlo8(&hb[8]);
    float po[4][5] = {};
    #pragma unroll
    for (int lt = 0; lt < 4; ++lt) {
        short8v wbr0 = *(const short8v*)&wpack[(lt*2+0)*64 + lane];
        short8v wbr1 = *(const short8v*)&wpack[(lt*2+1)*64 + lane];
        short8v wbz0 = *(const short8v*)&wpack[((lt+4)*2+0)*64 + lane];
        short8v wbz1 = *(const short8v*)&wpack[((lt+4)*2+1)*64 + lane];
        short8v wbn0 = *(const short8v*)&wpack[((lt+8)*2+0)*64 + lane];
        short8v wbn1 = *(const short8v*)&wpack[((lt+8)*2+1)*64 + lane];
        short8v vbr0 = *(const short8v*)&wpack[1536 + (lt*2+0)*64 + lane];
        short8v vbr1 = *(const short8v*)&wpack[1536 + (lt*2+1)*64 + lane];
        short8v vbz0 = *(const short8v*)&wpack[1536 + ((lt+4)*2+0)*64 + lane];
        short8v vbz1 = *(const short8v*)&wpack[1536 + ((lt+4)*2+1)*64 + lane];
        short8v vbn0 = *(const short8v*)&wpack[1536 + ((lt+8)*2+0)*64 + lane];
        short8v vbn1 = *(const short8v*)&wpack[1536 + ((lt+8)*2+1)*64 + lane];
        f32x4 aR  = {0.f,0.f,0.f,0.f};
        f32x4 aZ  = {0.f,0.f,0.f,0.f};
        f32x4 aNi = {0.f,0.f,0.f,0.f};
        f32x4 aNh = {0.f,0.f,0.f,0.f};
        aR = __builtin_amdgcn_mfma_f32_16x16x32_bf16(ya0h, wbr0, aR, 0, 0, 0);
        aR = __builtin_amdgcn_mfma_f32_16x16x32_bf16(ya1h, wbr1, aR, 0, 0, 0);
        aR = __builtin_amdgcn_mfma_f32_16x16x32_bf16(ya0l, wbr0, aR, 0, 0, 0);
        aR = __builtin_amdgcn_mfma_f32_16x16x32_bf16(ya1l, wbr1, aR, 0, 0, 0);
        aR = __builtin_amdgcn_mfma_f32_16x16x32_bf16(ha0h, vbr0, aR, 0, 0, 0);
        aR = __builtin_amdgcn_mfma_f32_16x16x32_bf16(ha1h, vbr1, aR, 0, 0, 0);
        aR = __builtin_amdgcn_mfma_f32_16x16x32_bf16(ha0l, vbr0, aR, 0, 0, 0);
        aR = __builtin_amdgcn_mfma_f32_16x16x32_bf16(ha1l, vbr1, aR, 0, 0, 0);
        aZ = __builtin_amdgcn_mfma_f32_16x16x32_bf16(ya0h, wbz0, aZ, 0, 0, 0);
        aZ = __builtin_amdgcn_mfma_f32_16x16x32_bf16(ya1h, wbz1, aZ, 0, 0, 0);
        aZ = __builtin_amdgcn_mfma_f32_16x16x32_bf16(ya0l, wbz0, aZ, 0, 0, 0);
        aZ = __builtin_amdgcn_mfma_f32_16x16x32_bf16(ya1l, wbz1, aZ, 0, 0, 0);
        aZ = __builtin_amdgcn_mfma_f32_16x16x32_bf16(ha0h, vbz0, aZ, 0, 0, 0);
        aZ = __builtin_amdgcn_mfma_f32_16x16x32_bf16(ha1h, vbz1, aZ, 0, 0, 0);
        aZ = __builtin_amdgcn_mfma_f32_16x16x32_bf16(ha0l, vbz0, aZ, 0, 0, 0);
        aZ = __builtin_amdgcn_mfma_f32_16x16x32_bf16(ha1l, vbz1, aZ, 0, 0, 0);
        aNi = __builtin_amdgcn_mfma_f32_16x16x32_bf16(ya0h, wbn0, aNi, 0, 0, 0);
        aNi = __builtin_amdgcn_mfma_f32_16x16x32_bf16(ya1h, wbn1, aNi, 0, 0, 0);
        aNi = __builtin_amdgcn_mfma_f32_16x16x32_bf16(ya0l, wbn0, aNi, 0, 0, 0);
        aNi = __builtin_amdgcn_mfma_f32_16x16x32_bf16(ya1l, wbn1, aNi, 0, 0, 0);
        aNh = __builtin_amdgcn_mfma_f32_16x16x32_bf16(ha0h, vbn0, aNh, 0, 0, 0);
        aNh = __builtin_amdgcn_mfma_f32_16x16x32_bf16(ha1h, vbn1, aNh, 0, 0, 0);
        aNh = __builtin_amdgcn_mfma_f32_16x16x32_bf16(ha0l, vbn0, aNh, 0, 0, 0);
        aNh = __builtin_amdgcn_mfma_f32_16x16x32_bf16(ha1l, vbn1, aNh, 0, 0, 0);
        int l = lt*16 + (lane & 15);
        float br = bih[l] + bhh[l];
        float bz = bih[64+l] + bhh[64+l];
        float bn = bih[128+l];
        float cn = bhh[128+l];
        float fw0 = fcw[l*5+0], fw1 = fcw[l*5+1], fw2 = fcw[l*5+2],
              fw3 = fcw[l*5+3], fw4 = fcw[l*5+4];
        #pragma unroll
        for (int r4 = 0; r4 < 4; ++r4) {
            int row = n0 + w*16 + (lane >> 4)*4 + r4;
            float rg = sigm(aR[r4] + br);
            float zg = sigm(aZ[r4] + bz);
            float ng = tanh_f(aNi[r4] + bn + rg*(aNh[r4] + cn));
            float hfv = h_in[(size_t)row*64 + l];
            float hnv = (1.f - zg)*ng + zg*hfv;
            hnew[(size_t)row*64 + l] = hnv;
            po[r4][0] += hnv*fw0; po[r4][1] += hnv*fw1; po[r4][2] += hnv*fw2;
            po[r4][3] += hnv*fw3; po[r4][4] += hnv*fw4;
        }
    }
    #pragma unroll
    for (int r4 = 0; r4 < 4; ++r4)
        #pragma unroll
        for (int j = 0; j < 5; ++j) {
            float v = po[r4][j];
            v += __shfl_xor(v, 1); v += __shfl_xor(v, 2);
            v += __shfl_xor(v, 4); v += __shfl_xor(v, 8);
            po[r4][j] = v;
        }
    if ((lane & 15) == 0) {
        #pragma unroll
        for (int r4 = 0; r4 < 4; ++r4) {
            int node = n0 + w*16 + (lane >> 4)*4 + r4;
            #pragma unroll
            for (int j = 0; j < 5; ++j) out[(size_t)node*5 + j] = po[r4][j] + fcb[j];
        }
    }
}

extern "C" void kernel_launch(void* const* d_in, const int* in_sizes, int n_in,
                              void* d_out, int out_size, void* d_ws, size_t ws_size,
                              hipStream_t stream) {
    const float* x   = (const float*)d_in[0];
    const float* ew  = (const float*)d_in[1];
    const float* h   = (const float*)d_in[2];
    const float* W1  = (const float*)d_in[3];
    const float* b1  = (const float*)d_in[4];
    const float* W2  = (const float*)d_in[5];
    const float* b2  = (const float*)d_in[6];
    const float* wih = (const float*)d_in[7];
    const float* whh = (const float*)d_in[8];
    const float* bih = (const float*)d_in[9];
    const float* bhh = (const float*)d_in[10];
    const float* fcw = (const float*)d_in[11];
    const float* fcb = (const float*)d_in[12];
    const int*   ei  = (const int*)d_in[13];
    const int* src = ei;
    const int* dst = ei + EE;

    // ws: A2p bf16 @0 (25.6MB) | epack @25.6MB (9.6MB) | wpack @35.2MB (48KB) | pk u64 @36MB (1.6MB)
    u32*   A2p   = (u32*)d_ws;
    uint2* epack = (uint2*)((char*)d_ws + 25600000);
    uint4* wpack = (uint4*)((char*)d_ws + 35200000);
    u64*   pk    = (u64*)((char*)d_ws + 36000000);
    // d_out head (first NTOT*5 floats, dead until k_gru epilogue) hosts CSR + scalars
    int*   cur  = (int*)d_out;                    // 200000 fill cursors
    int*   off  = cur + NTOT;                     // 200001
    int*   bsum = off + NTOT + 1;                 // 782
    float* dinv = (float*)d_out + 401024;
    float* sagg = (float*)d_out + 601024;
    float* out  = (float*)d_out;
    float* B2   = out + (size_t)NTOT*5;           // d_out tail: y2 buffer, finally hnew

    hipMemsetAsync(pk, 0, (size_t)NTOT*8, stream);
    k_degcnt<<<4688,  256, 0, stream>>>(ew, dst, pk);
    k_scan1 <<<782,   256, 0, stream>>>(pk, off, bsum, dinv);
    k_scan2 <<<1,    1024, 0, stream>>>(bsum);
    k_scan3 <<<782,   256, 0, stream>>>(off, bsum, cur);
    k_fill  <<<4688,  256, 0, stream>>>(src, dst, ew, dinv, cur, epack);
    k_sagg  <<<782,   256, 0, stream>>>(off, epack, x, dinv, sagg);
    k_wprep <<<12,    256, 0, stream>>>(wih, whh, wpack);
    k_l12   <<<3125,  256, 0, stream>>>(sagg, W1, b1, W2, A2p);
    k_gather<<<50000, 256, 0, stream>>>(A2p, epack, off, dinv, b2, B2);
    k_gru   <<<3125,  256, 0, stream>>>(B2, h, wpack, bih, bhh, fcw, fcb, out, B2);
}

// Round 13
// 279.541 us; speedup vs baseline: 12.1510x; 1.1148x over previous
//
#include <hip/hip_runtime.h>

#define NTOT 200000
#define EE   1200000

typedef unsigned int u32;
typedef unsigned long long u64;
typedef __attribute__((ext_vector_type(8))) short short8v;
typedef __attribute__((ext_vector_type(4))) float f32x4;

__device__ __forceinline__ float rcpf(float x) { return __builtin_amdgcn_rcpf(x); }
__device__ __forceinline__ float sigm(float x) { return rcpf(1.f + __expf(-x)); }
__device__ __forceinline__ float tanh_f(float x) { return 1.f - 2.f * rcpf(__expf(2.f * x) + 1.f); }
__device__ __forceinline__ u32 f2bf(float f) {           // RNE f32->bf16
    u32 u = __float_as_uint(f);
    return (u + 0x7fffu + ((u >> 16) & 1u)) >> 16;
}
__device__ __forceinline__ float bf2f(u32 b) { return __uint_as_float(b << 16); }
__device__ __forceinline__ float bf_lo(u32 p) { return __uint_as_float(p << 16); }
__device__ __forceinline__ float bf_hi(u32 p) { return __uint_as_float(p & 0xffff0000u); }

__device__ __forceinline__ short8v packhi8(const float* v) {
    union { u32 u[4]; short8v s; } r;
    r.u[0] = f2bf(v[0]) | (f2bf(v[1]) << 16);
    r.u[1] = f2bf(v[2]) | (f2bf(v[3]) << 16);
    r.u[2] = f2bf(v[4]) | (f2bf(v[5]) << 16);
    r.u[3] = f2bf(v[6]) | (f2bf(v[7]) << 16);
    return r.s;
}
__device__ __forceinline__ short8v packlo8(const float* v) {
    float q[8];
    #pragma unroll
    for (int i = 0; i < 8; ++i) q[i] = v[i] - bf2f(f2bf(v[i]));
    union { u32 u[4]; short8v s; } r;
    r.u[0] = f2bf(q[0]) | (f2bf(q[1]) << 16);
    r.u[1] = f2bf(q[2]) | (f2bf(q[3]) << 16);
    r.u[2] = f2bf(q[4]) | (f2bf(q[5]) << 16);
    r.u[3] = f2bf(q[6]) | (f2bf(q[7]) << 16);
    return r.s;
}

// ---------- degree+count in ONE u64 atomic; rank captured from the returned old value ----------
__global__ __launch_bounds__(256) void k_degcnt(const float* __restrict__ ew,
                                                const int* __restrict__ dst,
                                                u64* __restrict__ pk,
                                                u32* __restrict__ rank) {
    int e = blockIdx.x*256 + threadIdx.x;
    if (e < EE) {
        u64 v = (1ull << 40) | (u64)(u32)__float2uint_rn(ew[e] * 16777216.f);
        u64 old = atomicAdd(&pk[dst[e]], v);
        rank[e] = (u32)(old >> 40);          // # earlier edges with same dst
    }
}

// scan of counts (from pk) + dinv = rsqrt(1 + fixsum*2^-24) fused
__global__ __launch_bounds__(256) void k_scan1(const u64* __restrict__ pk,
                                               int* __restrict__ off,
                                               int* __restrict__ bsum,
                                               float* __restrict__ dinv) {
    __shared__ int s[256];
    int t = threadIdx.x, i = blockIdx.x*256 + t;
    int v = 0;
    if (i < NTOT) {
        u64 p = pk[i];
        v = (int)(p >> 40);
        dinv[i] = rsqrtf(1.0f + (float)(p & 0xFFFFFFFFFFull) * 5.9604644775390625e-8f);
    }
    s[t] = v; __syncthreads();
    #pragma unroll
    for (int o = 1; o < 256; o <<= 1) {
        int a = (t >= o) ? s[t-o] : 0; __syncthreads();
        s[t] += a; __syncthreads();
    }
    if (i < NTOT) off[i] = s[t] - v;
    if (t == 255) bsum[blockIdx.x] = s[255];
}

__global__ __launch_bounds__(1024) void k_scan2(int* bsum) {   // 782 totals
    __shared__ int s[1024];
    int t = threadIdx.x;
    int v = (t < 782) ? bsum[t] : 0;
    s[t] = v; __syncthreads();
    for (int o = 1; o < 1024; o <<= 1) {
        int a = (t >= o) ? s[t-o] : 0; __syncthreads();
        s[t] += a; __syncthreads();
    }
    if (t < 782) bsum[t] = s[t] - v;
}

__global__ __launch_bounds__(256) void k_scan3(int* __restrict__ off,
                                               const int* __restrict__ bsum) {
    int i = blockIdx.x*256 + threadIdx.x;
    if (i < NTOT) off[i] = off[i] + bsum[blockIdx.x];
    if (i == 0) off[NTOT] = EE;
}

// fill CSR slots with precomputed {src, norm} — NO atomics: slot = off[dst] + rank
__global__ __launch_bounds__(256) void k_fill(const int* __restrict__ src,
                                              const int* __restrict__ dst,
                                              const float* __restrict__ ew,
                                              const float* __restrict__ dinv,
                                              const int* __restrict__ off,
                                              const u32* __restrict__ rank,
                                              uint2* __restrict__ epack) {
    int e = blockIdx.x*256 + threadIdx.x;
    if (e >= EE) return;
    int d = dst[e], s = src[e];
    float norm = dinv[s] * ew[e] * dinv[d];
    int p = off[d] + (int)rank[e];
    epack[p] = make_uint2((u32)s, __float_as_uint(norm));
}

// layer-1 scalar aggregation (T=1 rank-1 trick)
__global__ __launch_bounds__(256) void k_sagg(const int* __restrict__ off,
                                              const uint2* __restrict__ epack,
                                              const float* __restrict__ x,
                                              const float* __restrict__ dinv,
                                              float* __restrict__ sagg) {
    int n = blockIdx.x*256 + threadIdx.x;
    if (n >= NTOT) return;
    int e0 = off[n], e1 = off[n+1];
    float s = 0.f;
    for (int e = e0; e < e1; ++e) {
        uint2 ep = epack[e];
        s += __uint_as_float(ep.y) * x[ep.x];
    }
    float di = dinv[n];
    sagg[n] = s + di*di*x[n];
}

// pack wih/whh into MFMA B-frag-linear bf16: tile tau (0..23 ih, 24..47 hh)
__global__ __launch_bounds__(256) void k_wprep(const float* __restrict__ wih,
                                               const float* __restrict__ whh,
                                               uint4* __restrict__ wpack) {
    int v = blockIdx.x*256 + threadIdx.x;
    if (v >= 3072) return;
    int lane = v & 63, tau = v >> 6;
    const float* W = (tau < 24) ? wih : whh;
    int tt = tau % 24;
    int lt = tt >> 1, ks = tt & 1;
    const float* s = W + (lt*16 + (lane & 15))*64 + ks*32 + (lane >> 4)*8;
    uint4 o;
    o.x = f2bf(s[0]) | (f2bf(s[1]) << 16);
    o.y = f2bf(s[2]) | (f2bf(s[3]) << 16);
    o.z = f2bf(s[4]) | (f2bf(s[5]) << 16);
    o.w = f2bf(s[6]) | (f2bf(s[7]) << 16);
    wpack[v] = o;
}

// fused: y1 = relu(sagg*W1 + b1)  ->  A2 = y1 @ W2, stored packed bf16 (128B/row)
__global__ __launch_bounds__(256) void k_l12(const float* __restrict__ sagg,
                                             const float* __restrict__ W1,
                                             const float* __restrict__ b1,
                                             const float* __restrict__ W2,
                                             u32* __restrict__ A2p) {
    __shared__ float ysh[64][68];
    __shared__ float wsh[64*68];              // W2 row k at k*68, f32
    int t = threadIdx.x;
    int n0 = blockIdx.x * 64;
    #pragma unroll
    for (int i = 0; i < 16; ++i) {
        int v = t + i*256;                    // coalesced global read of W2
        wsh[(v >> 6)*68 + (v & 63)] = W2[v];
    }
    {
        int row = t >> 2, c0 = (t & 3) * 16;
        float sv = sagg[n0 + row];
        #pragma unroll
        for (int q = 0; q < 4; ++q) {
            float4 w  = *(const float4*)(W1 + c0 + q*4);
            float4 bb = *(const float4*)(b1 + c0 + q*4);
            ysh[row][c0+q*4+0] = fmaxf(sv*w.x + bb.x, 0.f);
            ysh[row][c0+q*4+1] = fmaxf(sv*w.y + bb.y, 0.f);
            ysh[row][c0+q*4+2] = fmaxf(sv*w.z + bb.z, 0.f);
            ysh[row][c0+q*4+3] = fmaxf(sv*w.w + bb.w, 0.f);
        }
    }
    __syncthreads();
    int p = t >> 3, c = t & 7;
    float acc0[8], acc1[8];
    #pragma unroll
    for (int j = 0; j < 8; ++j) { acc0[j] = 0.f; acc1[j] = 0.f; }
    #pragma unroll 4
    for (int k = 0; k < 64; ++k) {
        float y0 = ysh[p][k], y1 = ysh[p+32][k];
        const float* wr = wsh + k*68 + c*8;
        float4 w0 = *(const float4*)wr;
        float4 w1 = *(const float4*)(wr + 4);
        acc0[0] += y0*w0.x; acc0[1] += y0*w0.y; acc0[2] += y0*w0.z; acc0[3] += y0*w0.w;
        acc0[4] += y0*w1.x; acc0[5] += y0*w1.y; acc0[6] += y0*w1.z; acc0[7] += y0*w1.w;
        acc1[0] += y1*w0.x; acc1[1] += y1*w0.y; acc1[2] += y1*w0.z; acc1[3] += y1*w0.w;
        acc1[4] += y1*w1.x; acc1[5] += y1*w1.y; acc1[6] += y1*w1.z; acc1[7] += y1*w1.w;
    }
    int na = n0 + p, nb = n0 + p + 32;
    uint4 pk;
    pk.x = f2bf(acc0[0]) | (f2bf(acc0[1]) << 16);
    pk.y = f2bf(acc0[2]) | (f2bf(acc0[3]) << 16);
    pk.z = f2bf(acc0[4]) | (f2bf(acc0[5]) << 16);
    pk.w = f2bf(acc0[6]) | (f2bf(acc0[7]) << 16);
    *(uint4*)(A2p + (size_t)na*32 + c*4) = pk;
    pk.x = f2bf(acc1[0]) | (f2bf(acc1[1]) << 16);
    pk.y = f2bf(acc1[2]) | (f2bf(acc1[3]) << 16);
    pk.z = f2bf(acc1[4]) | (f2bf(acc1[5]) << 16);
    pk.w = f2bf(acc1[6]) | (f2bf(acc1[7]) << 16);
    *(uint4*)(A2p + (size_t)nb*32 + c*4) = pk;
}

// CSR gather, 4-edge ILP, bf16 rows
__global__ __launch_bounds__(256) void k_gather(const u32* __restrict__ A2p,
                                                const uint2* __restrict__ epack,
                                                const int* __restrict__ off,
                                                const float* __restrict__ dinv,
                                                const float* __restrict__ b2,
                                                float* __restrict__ B2) {
    int wv = (blockIdx.x*256 + threadIdx.x) >> 6;
    int lane = threadIdx.x & 63;
    if (wv >= NTOT) return;
    int g = lane >> 4, q = lane & 15;
    int e0 = off[wv], e1 = off[wv+1];
    float ax = 0.f, ay = 0.f, az = 0.f, aw = 0.f;
    for (int e = e0 + g; e < e1; e += 4) {
        uint2 ep = epack[e];
        int sr = (int)ep.x;
        float nrm = __uint_as_float(ep.y);
        uint2 pw = *(const uint2*)(A2p + (size_t)sr*32 + q*2);
        ax += nrm*bf_lo(pw.x); ay += nrm*bf_hi(pw.x);
        az += nrm*bf_lo(pw.y); aw += nrm*bf_hi(pw.y);
    }
    ax += __shfl_xor(ax, 16); ax += __shfl_xor(ax, 32);
    ay += __shfl_xor(ay, 16); ay += __shfl_xor(ay, 32);
    az += __shfl_xor(az, 16); az += __shfl_xor(az, 32);
    aw += __shfl_xor(aw, 16); aw += __shfl_xor(aw, 32);
    if (g == 0) {
        float di = dinv[wv], d2 = di*di;
        uint2 pw = *(const uint2*)(A2p + (size_t)wv*32 + q*2);
        float4 bb = *(const float4*)(b2 + q*4);
        float4 o;
        o.x = fmaxf(ax + d2*bf_lo(pw.x) + bb.x, 0.f);
        o.y = fmaxf(ay + d2*bf_hi(pw.x) + bb.y, 0.f);
        o.z = fmaxf(az + d2*bf_lo(pw.y) + bb.z, 0.f);
        o.w = fmaxf(aw + d2*bf_hi(pw.y) + bb.w, 0.f);
        *(float4*)(B2 + (size_t)wv*64 + q*4) = o;
    }
}

// ---------- MFMA GRU + FC head (round-8 proven) ----------
__global__ __launch_bounds__(256) void k_gru(const float* B2,
                                             const float* __restrict__ h_in,
                                             const uint4* __restrict__ wpack,
                                             const float* __restrict__ bih,
                                             const float* __restrict__ bhh,
                                             const float* __restrict__ fcw,
                                             const float* __restrict__ fcb,
                                             float* __restrict__ out,
                                             float* hnew) {
    int t = threadIdx.x;
    int lane = t & 63, w = t >> 6;
    int n0 = blockIdx.x * 64;
    int rowA = n0 + w*16 + (lane & 15);
    int kb = (lane >> 4) * 8;
    float yf[16], hb[16];
    {
        const float4* yp = (const float4*)(B2 + (size_t)rowA*64 + kb);
        const float4* hp = (const float4*)(h_in + (size_t)rowA*64 + kb);
        *(float4*)&yf[0]  = yp[0]; *(float4*)&yf[4]  = yp[1];
        *(float4*)&yf[8]  = yp[8]; *(float4*)&yf[12] = yp[9];   // +32 floats
        *(float4*)&hb[0]  = hp[0]; *(float4*)&hb[4]  = hp[1];
        *(float4*)&hb[8]  = hp[8]; *(float4*)&hb[12] = hp[9];
    }
    short8v ya0h = packhi8(&yf[0]), ya1h = packhi8(&yf[8]);
    short8v ya0l = packlo8(&yf[0]), ya1l = packlo8(&yf[8]);
    short8v ha0h = packhi8(&hb[0]), ha1h = packhi8(&hb[8]);
    short8v ha0l = packlo8(&hb[0]), ha1l = packlo8(&hb[8]);
    float po[4][5] = {};
    #pragma unroll
    for (int lt = 0; lt < 4; ++lt) {
        short8v wbr0 = *(const short8v*)&wpack[(lt*2+0)*64 + lane];
        short8v wbr1 = *(const short8v*)&wpack[(lt*2+1)*64 + lane];
        short8v wbz0 = *(const short8v*)&wpack[((lt+4)*2+0)*64 + lane];
        short8v wbz1 = *(const short8v*)&wpack[((lt+4)*2+1)*64 + lane];
        short8v wbn0 = *(const short8v*)&wpack[((lt+8)*2+0)*64 + lane];
        short8v wbn1 = *(const short8v*)&wpack[((lt+8)*2+1)*64 + lane];
        short8v vbr0 = *(const short8v*)&wpack[1536 + (lt*2+0)*64 + lane];
        short8v vbr1 = *(const short8v*)&wpack[1536 + (lt*2+1)*64 + lane];
        short8v vbz0 = *(const short8v*)&wpack[1536 + ((lt+4)*2+0)*64 + lane];
        short8v vbz1 = *(const short8v*)&wpack[1536 + ((lt+4)*2+1)*64 + lane];
        short8v vbn0 = *(const short8v*)&wpack[1536 + ((lt+8)*2+0)*64 + lane];
        short8v vbn1 = *(const short8v*)&wpack[1536 + ((lt+8)*2+1)*64 + lane];
        f32x4 aR  = {0.f,0.f,0.f,0.f};
        f32x4 aZ  = {0.f,0.f,0.f,0.f};
        f32x4 aNi = {0.f,0.f,0.f,0.f};
        f32x4 aNh = {0.f,0.f,0.f,0.f};
        aR = __builtin_amdgcn_mfma_f32_16x16x32_bf16(ya0h, wbr0, aR, 0, 0, 0);
        aR = __builtin_amdgcn_mfma_f32_16x16x32_bf16(ya1h, wbr1, aR, 0, 0, 0);
        aR = __builtin_amdgcn_mfma_f32_16x16x32_bf16(ya0l, wbr0, aR, 0, 0, 0);
        aR = __builtin_amdgcn_mfma_f32_16x16x32_bf16(ya1l, wbr1, aR, 0, 0, 0);
        aR = __builtin_amdgcn_mfma_f32_16x16x32_bf16(ha0h, vbr0, aR, 0, 0, 0);
        aR = __builtin_amdgcn_mfma_f32_16x16x32_bf16(ha1h, vbr1, aR, 0, 0, 0);
        aR = __builtin_amdgcn_mfma_f32_16x16x32_bf16(ha0l, vbr0, aR, 0, 0, 0);
        aR = __builtin_amdgcn_mfma_f32_16x16x32_bf16(ha1l, vbr1, aR, 0, 0, 0);
        aZ = __builtin_amdgcn_mfma_f32_16x16x32_bf16(ya0h, wbz0, aZ, 0, 0, 0);
        aZ = __builtin_amdgcn_mfma_f32_16x16x32_bf16(ya1h, wbz1, aZ, 0, 0, 0);
        aZ = __builtin_amdgcn_mfma_f32_16x16x32_bf16(ya0l, wbz0, aZ, 0, 0, 0);
        aZ = __builtin_amdgcn_mfma_f32_16x16x32_bf16(ya1l, wbz1, aZ, 0, 0, 0);
        aZ = __builtin_amdgcn_mfma_f32_16x16x32_bf16(ha0h, vbz0, aZ, 0, 0, 0);
        aZ = __builtin_amdgcn_mfma_f32_16x16x32_bf16(ha1h, vbz1, aZ, 0, 0, 0);
        aZ = __builtin_amdgcn_mfma_f32_16x16x32_bf16(ha0l, vbz0, aZ, 0, 0, 0);
        aZ = __builtin_amdgcn_mfma_f32_16x16x32_bf16(ha1l, vbz1, aZ, 0, 0, 0);
        aNi = __builtin_amdgcn_mfma_f32_16x16x32_bf16(ya0h, wbn0, aNi, 0, 0, 0);
        aNi = __builtin_amdgcn_mfma_f32_16x16x32_bf16(ya1h, wbn1, aNi, 0, 0, 0);
        aNi = __builtin_amdgcn_mfma_f32_16x16x32_bf16(ya0l, wbn0, aNi, 0, 0, 0);
        aNi = __builtin_amdgcn_mfma_f32_16x16x32_bf16(ya1l, wbn1, aNi, 0, 0, 0);
        aNh = __builtin_amdgcn_mfma_f32_16x16x32_bf16(ha0h, vbn0, aNh, 0, 0, 0);
        aNh = __builtin_amdgcn_mfma_f32_16x16x32_bf16(ha1h, vbn1, aNh, 0, 0, 0);
        aNh = __builtin_amdgcn_mfma_f32_16x16x32_bf16(ha0l, vbn0, aNh, 0, 0, 0);
        aNh = __builtin_amdgcn_mfma_f32_16x16x32_bf16(ha1l, vbn1, aNh, 0, 0, 0);
        int l = lt*16 + (lane & 15);
        float br = bih[l] + bhh[l];
        float bz = bih[64+l] + bhh[64+l];
        float bn = bih[128+l];
        float cn = bhh[128+l];
        float fw0 = fcw[l*5+0], fw1 = fcw[l*5+1], fw2 = fcw[l*5+2],
              fw3 = fcw[l*5+3], fw4 = fcw[l*5+4];
        #pragma unroll
        for (int r4 = 0; r4 < 4; ++r4) {
            int row = n0 + w*16 + (lane >> 4)*4 + r4;
            float rg = sigm(aR[r4] + br);
            float zg = sigm(aZ[r4] + bz);
            float ng = tanh_f(aNi[r4] + bn + rg*(aNh[r4] + cn));
            float hfv = h_in[(size_t)row*64 + l];
            float hnv = (1.f - zg)*ng + zg*hfv;
            hnew[(size_t)row*64 + l] = hnv;
            po[r4][0] += hnv*fw0; po[r4][1] += hnv*fw1; po[r4][2] += hnv*fw2;
            po[r4][3] += hnv*fw3; po[r4][4] += hnv*fw4;
        }
    }
    #pragma unroll
    for (int r4 = 0; r4 < 4; ++r4)
        #pragma unroll
        for (int j = 0; j < 5; ++j) {
            float v = po[r4][j];
            v += __shfl_xor(v, 1); v += __shfl_xor(v, 2);
            v += __shfl_xor(v, 4); v += __shfl_xor(v, 8);
            po[r4][j] = v;
        }
    if ((lane & 15) == 0) {
        #pragma unroll
        for (int r4 = 0; r4 < 4; ++r4) {
            int node = n0 + w*16 + (lane >> 4)*4 + r4;
            #pragma unroll
            for (int j = 0; j < 5; ++j) out[(size_t)node*5 + j] = po[r4][j] + fcb[j];
        }
    }
}

extern "C" void kernel_launch(void* const* d_in, const int* in_sizes, int n_in,
                              void* d_out, int out_size, void* d_ws, size_t ws_size,
                              hipStream_t stream) {
    const float* x   = (const float*)d_in[0];
    const float* ew  = (const float*)d_in[1];
    const float* h   = (const float*)d_in[2];
    const float* W1  = (const float*)d_in[3];
    const float* b1  = (const float*)d_in[4];
    const float* W2  = (const float*)d_in[5];
    const float* b2  = (const float*)d_in[6];
    const float* wih = (const float*)d_in[7];
    const float* whh = (const float*)d_in[8];
    const float* bih = (const float*)d_in[9];
    const float* bhh = (const float*)d_in[10];
    const float* fcw = (const float*)d_in[11];
    const float* fcb = (const float*)d_in[12];
    const int*   ei  = (const int*)d_in[13];
    const int* src = ei;
    const int* dst = ei + EE;

    // ws: A2p bf16 @0 (25.6MB) | epack @25.6MB (9.6MB) | wpack @35.2MB (48KB)
    //     | pk u64 @36MB (1.6MB) | rank @38MB (4.8MB)
    u32*   A2p   = (u32*)d_ws;
    uint2* epack = (uint2*)((char*)d_ws + 25600000);
    uint4* wpack = (uint4*)((char*)d_ws + 35200000);
    u64*   pk    = (u64*)((char*)d_ws + 36000000);
    u32*   rank  = (u32*)((char*)d_ws + 38000000);
    // d_out head (first NTOT*5 floats, dead until k_gru epilogue) hosts CSR + scalars
    int*   off  = (int*)d_out;                    // 200001
    int*   bsum = off + NTOT + 1;                 // 782
    float* dinv = (float*)d_out + 401024;
    float* sagg = (float*)d_out + 601024;
    float* out  = (float*)d_out;
    float* B2   = out + (size_t)NTOT*5;           // d_out tail: y2 buffer, finally hnew

    hipMemsetAsync(pk, 0, (size_t)NTOT*8, stream);
    k_degcnt<<<4688,  256, 0, stream>>>(ew, dst, pk, rank);
    k_scan1 <<<782,   256, 0, stream>>>(pk, off, bsum, dinv);
    k_scan2 <<<1,    1024, 0, stream>>>(bsum);
    k_scan3 <<<782,   256, 0, stream>>>(off, bsum);
    k_fill  <<<4688,  256, 0, stream>>>(src, dst, ew, dinv, off, rank, epack);
    k_sagg  <<<782,   256, 0, stream>>>(off, epack, x, dinv, sagg);
    k_wprep <<<12,    256, 0, stream>>>(wih, whh, wpack);
    k_l12   <<<3125,  256, 0, stream>>>(sagg, W1, b1, W2, A2p);
    k_gather<<<50000, 256, 0, stream>>>(A2p, epack, off, dinv, b2, B2);
    k_gru   <<<3125,  256, 0, stream>>>(B2, h, wpack, bih, bhh, fcw, fcb, out, B2);
}